// Round 2
// baseline (1735.157 us; speedup 1.0000x reference)
//
#include <hip/hip_runtime.h>
#include <math.h>

#define BB 2
#define TT 1024
#define CC 384
#define HH 4
#define DD 96
#define EE 8
#define FFD 1536
#define NROW (BB*TT)
#define QKVN (3*CC)
#define NSLOT (NROW*2)

// ---------- helpers ----------
__device__ __forceinline__ float wredSum64(float v) {
#pragma unroll
  for (int o = 32; o > 0; o >>= 1) v += __shfl_xor(v, o, 64);
  return v;
}
__device__ __forceinline__ float rsum16(float v) {
#pragma unroll
  for (int o = 8; o > 0; o >>= 1) v += __shfl_xor(v, o, 16);
  return v;
}
__device__ __forceinline__ float rmax16(float v) {
#pragma unroll
  for (int o = 8; o > 0; o >>= 1) v = fmaxf(v, __shfl_xor(v, o, 16));
  return v;
}
__device__ __forceinline__ float dot4f(const float4 a, const float4 b) {
  return a.x*b.x + a.y*b.y + a.z*b.z + a.w*b.w;
}
__device__ __forceinline__ float blockRed128(float v, float* red) {
  v = wredSum64(v);
  const int w = threadIdx.x >> 6;
  if ((threadIdx.x & 63) == 0) red[w] = v;
  __syncthreads();
  float r = red[0] + red[1];
  __syncthreads();
  return r;
}
__device__ __forceinline__ float elup1(float x) {  // elu(x)+1
  return x > 0.f ? x + 1.f : expf(x);
}

// ---------- kernel: zero routing counters ----------
__global__ void zero_counts_kernel(int* counts) {
  if (threadIdx.x < EE) counts[threadIdx.x] = 0;
}

// ---------- kernel: LayerNorm over C (one wave per row) ----------
__global__ __launch_bounds__(64) void ln_row_kernel(
    const float* __restrict__ xin, const float* __restrict__ g,
    const float* __restrict__ b, float* __restrict__ xout) {
  const int row = blockIdx.x;
  const int lane = threadIdx.x;
  const size_t base = (size_t)row * CC;
  float v[6];
#pragma unroll
  for (int p = 0; p < 6; ++p) v[p] = xin[base + lane + 64 * p];
  float s = v[0] + v[1] + v[2] + v[3] + v[4] + v[5];
  s = wredSum64(s);
  const float mu = s * (1.f / CC);
  float sq = 0.f;
#pragma unroll
  for (int p = 0; p < 6; ++p) { float d = v[p] - mu; sq += d * d; }
  sq = wredSum64(sq);
  const float rinv = rsqrtf(sq * (1.f / CC) + 1e-5f);
#pragma unroll
  for (int p = 0; p < 6; ++p) {
    const int c = lane + 64 * p;
    xout[base + c] = (v[p] - mu) * rinv * g[c] + b[c];
  }
}

// ---------- kernel: QKV GEMM 2048x1152x384 (fp32, tiled) ----------
__global__ __launch_bounds__(256) void gemm_qkv_kernel(
    const float* __restrict__ A, const float* __restrict__ Bw,
    const float* __restrict__ bias, float* __restrict__ Cout) {
  const int N = QKVN, K = CC;
  const int n0 = blockIdx.x * 64, m0 = blockIdx.y * 64;
  __shared__ float As[16][68];
  __shared__ float Bs[16][64];
  const int tid = threadIdx.x, tx = tid & 15, ty = tid >> 4;
  const int akk = tid & 15, am = tid >> 4;
  const int bn = tid & 63, bk = tid >> 6;
  float acc[4][4] = {};
  for (int k0 = 0; k0 < K; k0 += 16) {
#pragma unroll
    for (int q = 0; q < 4; ++q) {
      As[akk][am + 16 * q] = A[(size_t)(m0 + am + 16 * q) * K + k0 + akk];
      Bs[bk + 4 * q][bn] = Bw[(size_t)(k0 + bk + 4 * q) * N + n0 + bn];
    }
    __syncthreads();
#pragma unroll
    for (int kk = 0; kk < 16; ++kk) {
      const float4 av = *(const float4*)&As[kk][ty * 4];
      const float4 bv = *(const float4*)&Bs[kk][tx * 4];
      const float aa[4] = {av.x, av.y, av.z, av.w};
      const float bb4[4] = {bv.x, bv.y, bv.z, bv.w};
#pragma unroll
      for (int i = 0; i < 4; ++i)
#pragma unroll
        for (int jj = 0; jj < 4; ++jj) acc[i][jj] += aa[i] * bb4[jj];
    }
    __syncthreads();
  }
#pragma unroll
  for (int i = 0; i < 4; ++i) {
    const int r = m0 + ty * 4 + i;
#pragma unroll
    for (int jj = 0; jj < 4; ++jj) {
      const int c = n0 + tx * 4 + jj;
      Cout[(size_t)r * N + c] = acc[i][jj] + bias[c];
    }
  }
}

// ---------- kernel: RoPE + elu+1 features ----------
__global__ __launch_bounds__(256) void rope_kernel(
    const float* __restrict__ qkv, float* __restrict__ qr, float* __restrict__ kr,
    float* __restrict__ qp, float* __restrict__ kp) {
  const int gid = blockIdx.x * 256 + threadIdx.x;  // B*H*T*48
  const int i = gid % 48;
  const int t = (gid / 48) % TT;
  const int h = (gid / (48 * TT)) % HH;
  const int b = gid / (48 * TT * HH);
  const float inv = 1.0f / powf(10000.0f, (float)i * (1.0f / 48.0f));
  const float ang = (float)t * inv;
  float sn, cs;
  sincosf(ang, &sn, &cs);
  const float* row = qkv + ((size_t)(b * TT + t)) * QKVN + h * DD;
  const float q1 = row[i], q2 = row[i + 48];
  const float k1 = row[CC + i], k2 = row[CC + i + 48];
  const float qo1 = q1 * cs - q2 * sn, qo2 = q2 * cs + q1 * sn;
  const float ko1 = k1 * cs - k2 * sn, ko2 = k2 * cs + k1 * sn;
  const size_t ob = ((size_t)((b * HH + h) * TT + t)) * DD;
  qr[ob + i] = qo1; qr[ob + i + 48] = qo2;
  kr[ob + i] = ko1; kr[ob + i + 48] = ko2;
  const float scale = 0.10206207261596577f;  // 1/sqrt(96)
  qp[ob + i] = elup1(qo1 * scale); qp[ob + i + 48] = elup1(qo2 * scale);
  kp[ob + i] = elup1(ko1 * scale); kp[ob + i + 48] = elup1(ko2 * scale);
}

// ---------- kernel: fused dual attention (sharp softmax + linear) ----------
// grid: (32 q-tiles, 8 bh); 256 threads; TQ=32 rows, SB=32 s-chunk
// Identity: linear-attn cumsum path == second unnormalized causal attention.
__global__ __launch_bounds__(256) void attn_kernel(
    const float* __restrict__ qr, const float* __restrict__ kr,
    const float* __restrict__ qp, const float* __restrict__ kp,
    const float* __restrict__ qkv, const float* __restrict__ ang,
    const float* __restrict__ anb, const float* __restrict__ fgp,
    float* __restrict__ y_attn) {
  __shared__ float Qt[32][96];
  __shared__ float Qpt[32][96];
  __shared__ float Kt[32][100];   // reused as V tile in PV phase
  __shared__ float Kpt[32][100];
  __shared__ float Ps[32][34];
  __shared__ float Pl[32][34];
  const int bh = blockIdx.y, b = bh >> 2, h = bh & 3;
  const int qt = blockIdx.x, t0 = qt << 5;
  const int tid = threadIdx.x, j = tid & 15, rg = tid >> 4;
  const size_t qbase = ((size_t)bh * TT + t0) * DD;
#pragma unroll
  for (int p = 0; p < 12; ++p) {
    const int i = tid + 256 * p, r = i / 96, d = i - r * 96;
    Qt[r][d] = qr[qbase + i];
    Qpt[r][d] = qp[qbase + i];
  }
  float accS[2][6] = {}, accN[2][6] = {};
  float mrow[2] = {-1e30f, -1e30f}, lrow[2] = {0.f, 0.f}, den[2] = {0.f, 0.f};
  float* KtF = &Kt[0][0];
  __syncthreads();
  for (int c = 0; c <= qt; ++c) {
    const int s0 = c << 5;
    float vreg[12];
    const float* vb = qkv + ((size_t)(b * TT + s0)) * QKVN + 2 * CC + h * DD;
    const size_t kb = ((size_t)bh * TT + s0) * DD;
#pragma unroll
    for (int p = 0; p < 12; ++p) {
      const int i = tid + 256 * p, s = i / 96, d = i - s * 96;
      vreg[p] = vb[(size_t)s * QKVN + d];
      Kt[s][d] = kr[kb + i];
      Kpt[s][d] = kp[kb + i];
    }
    __syncthreads();
    float ds00 = 0, ds01 = 0, ds10 = 0, ds11 = 0;
    float dl00 = 0, dl01 = 0, dl10 = 0, dl11 = 0;
#pragma unroll
    for (int dd = 0; dd < 96; dd += 4) {
      const float4 qa = *(const float4*)&Qt[rg][dd];
      const float4 qb = *(const float4*)&Qt[rg + 16][dd];
      const float4 ka = *(const float4*)&Kt[j][dd];
      const float4 k2 = *(const float4*)&Kt[j + 16][dd];
      ds00 += dot4f(qa, ka); ds01 += dot4f(qa, k2);
      ds10 += dot4f(qb, ka); ds11 += dot4f(qb, k2);
      const float4 pa = *(const float4*)&Qpt[rg][dd];
      const float4 pb = *(const float4*)&Qpt[rg + 16][dd];
      const float4 fa = *(const float4*)&Kpt[j][dd];
      const float4 f2 = *(const float4*)&Kpt[j + 16][dd];
      dl00 += dot4f(pa, fa); dl01 += dot4f(pa, f2);
      dl10 += dot4f(pb, fa); dl11 += dot4f(pb, f2);
    }
    const float scale = 0.10206207261596577f;
    float sc00 = ds00 * scale, sc01 = ds01 * scale;
    float sc10 = ds10 * scale, sc11 = ds11 * scale;
    if (c == qt) {  // diagonal chunk: col > row masking
      if (j > rg) { sc00 = -1e30f; dl00 = 0.f; }        // col j   vs row rg
      { sc01 = -1e30f; dl01 = 0.f; }                    // col j+16 > rg always
      if (j > rg) { sc11 = -1e30f; dl11 = 0.f; }        // col j+16 vs row rg+16
      // col j vs row rg+16: j<16<=rg+16 -> never masked
    }
    // --- sharp online softmax + linear accumulate, per row group ---
    {
      const float cm = rmax16(fmaxf(sc00, sc01));
      const float mn = fmaxf(mrow[0], cm);
      const float sf = expf(mrow[0] - mn);
      const float p0 = expf(sc00 - mn), p1 = expf(sc01 - mn);
      lrow[0] = lrow[0] * sf + rsum16(p0 + p1);
      mrow[0] = mn;
      den[0] += rsum16(dl00 + dl01);
#pragma unroll
      for (int u = 0; u < 6; ++u) accS[0][u] *= sf;
      Ps[rg][j] = p0; Ps[rg][j + 16] = p1;
      Pl[rg][j] = dl00; Pl[rg][j + 16] = dl01;
    }
    {
      const float cm = rmax16(fmaxf(sc10, sc11));
      const float mn = fmaxf(mrow[1], cm);
      const float sf = expf(mrow[1] - mn);
      const float p0 = expf(sc10 - mn), p1 = expf(sc11 - mn);
      lrow[1] = lrow[1] * sf + rsum16(p0 + p1);
      mrow[1] = mn;
      den[1] += rsum16(dl10 + dl11);
#pragma unroll
      for (int u = 0; u < 6; ++u) accS[1][u] *= sf;
      Ps[rg + 16][j] = p0; Ps[rg + 16][j + 16] = p1;
      Pl[rg + 16][j] = dl10; Pl[rg + 16][j + 16] = dl11;
    }
    __syncthreads();  // scores done reading Kt; Ps/Pl visible
    // V into Kt space
#pragma unroll
    for (int p = 0; p < 12; ++p) {
      const int i = tid + 256 * p, s = i / 96, d = i - s * 96;
      KtF[s * 100 + d] = vreg[p];
    }
    __syncthreads();
    // PV
    const int c0 = j * 6;
#pragma unroll
    for (int s = 0; s < 32; s += 2) {
      const float2 pA = *(const float2*)&Ps[rg][s];
      const float2 pB = *(const float2*)&Ps[rg + 16][s];
      const float2 lA = *(const float2*)&Pl[rg][s];
      const float2 lB = *(const float2*)&Pl[rg + 16][s];
      const float* v0p = &KtF[s * 100 + c0];
      const float* v1p = v0p + 100;
      float va[6], vb2[6];
      *(float2*)&va[0] = *(const float2*)(v0p);
      *(float2*)&va[2] = *(const float2*)(v0p + 2);
      *(float2*)&va[4] = *(const float2*)(v0p + 4);
      *(float2*)&vb2[0] = *(const float2*)(v1p);
      *(float2*)&vb2[2] = *(const float2*)(v1p + 2);
      *(float2*)&vb2[4] = *(const float2*)(v1p + 4);
#pragma unroll
      for (int u = 0; u < 6; ++u) {
        accS[0][u] += pA.x * va[u] + pA.y * vb2[u];
        accS[1][u] += pB.x * va[u] + pB.y * vb2[u];
        accN[0][u] += lA.x * va[u] + lA.y * vb2[u];
        accN[1][u] += lB.x * va[u] + lB.y * vb2[u];
      }
    }
    __syncthreads();  // PV done before next chunk overwrites tiles
  }
  // epilogue: normalize, LN(y_lin), gated combine
  const float a = 1.f / (1.f + expf(-fgp[0]));
#pragma unroll
  for (int ri = 0; ri < 2; ++ri) {
    const int r = rg + 16 * ri, t = t0 + r;
    const float invl = 1.0f / lrow[ri];
    const float dinv = 1.0f / (den[ri] + 1e-4f);
    float yl[6];
    float s1 = 0.f;
#pragma unroll
    for (int u = 0; u < 6; ++u) { yl[u] = accN[ri][u] * dinv; s1 += yl[u]; }
    s1 = rsum16(s1);
    const float mu = s1 * (1.f / DD);
    float s2 = 0.f;
#pragma unroll
    for (int u = 0; u < 6; ++u) { const float d = yl[u] - mu; s2 += d * d; }
    s2 = rsum16(s2);
    const float rr = rsqrtf(s2 * (1.f / DD) + 1e-5f);
    const size_t ob = ((size_t)(b * TT + t)) * CC + h * DD + j * 6;
#pragma unroll
    for (int u = 0; u < 6; ++u) {
      const float ylin = (yl[u] - mu) * rr * ang[j * 6 + u] + anb[j * 6 + u];
      const float ys = accS[ri][u] * invl;
      y_attn[ob + u] = a * ys + (1.f - a) * ylin;
    }
  }
}

// ---------- kernel: out-LN + HBS + residual + LN2 + gate top-2 ----------
__global__ __launch_bounds__(128) void hbs_kernel(
    const float* __restrict__ y_attn, const float* __restrict__ x,
    const float* __restrict__ outg, const float* __restrict__ outb,
    const float* __restrict__ preg, const float* __restrict__ preb,
    const float* __restrict__ blocks, const float* __restrict__ wrow,
    const float* __restrict__ wcol, const float* __restrict__ alphap,
    const float* __restrict__ biasv, const float* __restrict__ ln2g,
    const float* __restrict__ ln2b, const float* __restrict__ gatew,
    float* __restrict__ hout, float* __restrict__ xn2,
    int* __restrict__ tok_idx, float* __restrict__ tok_w, int* __restrict__ counts) {
  __shared__ float flatS[CC];
  __shared__ float ybuf[CC];
  __shared__ float xbuf[CC];
  __shared__ float tmp[400];
  __shared__ float red[2];
  __shared__ float logit[EE];
  const int row = blockIdx.x, tid = threadIdx.x;
  const size_t base = (size_t)row * CC;
  float v[3];
#pragma unroll
  for (int p = 0; p < 3; ++p) v[p] = y_attn[base + tid + 128 * p];
  // LN(out_norm)
  float s = blockRed128(v[0] + v[1] + v[2], red);
  float mu = s * (1.f / CC);
  float sq = 0.f;
#pragma unroll
  for (int p = 0; p < 3; ++p) { const float d = v[p] - mu; sq += d * d; }
  sq = blockRed128(sq, red);
  float rin = rsqrtf(sq * (1.f / CC) + 1e-5f);
  float w[3];
#pragma unroll
  for (int p = 0; p < 3; ++p) {
    const int c = tid + 128 * p;
    w[p] = (v[p] - mu) * rin * outg[c] + outb[c];
  }
  // LN(pre)
  s = blockRed128(w[0] + w[1] + w[2], red);
  mu = s * (1.f / CC);
  sq = 0.f;
#pragma unroll
  for (int p = 0; p < 3; ++p) { const float d = w[p] - mu; sq += d * d; }
  sq = blockRed128(sq, red);
  rin = rsqrtf(sq * (1.f / CC) + 1e-5f);
#pragma unroll
  for (int p = 0; p < 3; ++p) {
    const int c = tid + 128 * p;
    flatS[c] = (w[p] - mu) * rin * preg[c] + preb[c];
  }
  __syncthreads();
  // block mixing: y[g,c] = sum_b flat[g*16+b]*blocks[g,b,c]
#pragma unroll
  for (int p = 0; p < 3; ++p) {
    const int o = tid + 128 * p;
    const int g = o >> 4, cc = o & 15;
    const float* bp = blocks + g * 256 + cc;
    const float* fp = flatS + g * 16;
    float acc = 0.f;
#pragma unroll
    for (int bb = 0; bb < 16; ++bb) acc += fp[bb] * bp[bb * 16];
    ybuf[o] = acc;
  }
  // monarch stage 1: tmp[i,k] = sum_j grid[i,j]*wcol[j,k]
#pragma unroll
  for (int p = 0; p < 4; ++p) {
    const int o = tid + 128 * p;
    if (o < 400) {
      const int i = o / 20, k = o - i * 20;
      float acc = 0.f;
#pragma unroll
      for (int jj = 0; jj < 20; ++jj) {
        const int src = i * 20 + jj;
        const float gv = (src < CC) ? flatS[src] : 0.f;
        acc += gv * wcol[jj * 20 + k];
      }
      tmp[o] = acc;
    }
  }
  __syncthreads();
  const float alpha = alphap[0];
  float hr[3];
#pragma unroll
  for (int p = 0; p < 3; ++p) {
    const int o = tid + 128 * p;
    const int i = o / 20, ll = o - i * 20;
    float mon = 0.f;
#pragma unroll
    for (int k = 0; k < 20; ++k) mon += tmp[i * 20 + k] * wrow[ll * 20 + k];
    const float hb = ybuf[383 - o] + alpha * mon + biasv[o];
    const float hv = x[base + o] + hb;
    hout[base + o] = hv;
    hr[p] = hv;
  }
  // LN2
  s = blockRed128(hr[0] + hr[1] + hr[2], red);
  mu = s * (1.f / CC);
  sq = 0.f;
#pragma unroll
  for (int p = 0; p < 3; ++p) { const float d = hr[p] - mu; sq += d * d; }
  sq = blockRed128(sq, red);
  rin = rsqrtf(sq * (1.f / CC) + 1e-5f);
#pragma unroll
  for (int p = 0; p < 3; ++p) {
    const int c = tid + 128 * p;
    const float xv = (hr[p] - mu) * rin * ln2g[c] + ln2b[c];
    xn2[base + c] = xv;
    xbuf[c] = xv;
  }
  __syncthreads();
  // gate logits
  const int e = tid >> 4, jj = tid & 15;
  float part = 0.f;
  for (int c = jj; c < CC; c += 16) part += xbuf[c] * gatew[c * EE + e];
  part = rsum16(part);
  if (jj == 0) logit[e] = fminf(20.f, fmaxf(-20.f, part));
  __syncthreads();
  if (tid == 0) {
    float lg[EE];
#pragma unroll
    for (int ee = 0; ee < EE; ++ee) lg[ee] = logit[ee];
    int i0 = 0; float v0 = lg[0];
#pragma unroll
    for (int ee = 1; ee < EE; ++ee) if (lg[ee] > v0) { v0 = lg[ee]; i0 = ee; }
    int i1 = -1; float v1 = -1e30f;
#pragma unroll
    for (int ee = 0; ee < EE; ++ee)
      if (ee != i0 && lg[ee] > v1) { v1 = lg[ee]; i1 = ee; }
    const float e1 = expf(v1 - v0);
    const float w0 = 1.f / (1.f + e1), w1 = e1 / (1.f + e1);
    tok_idx[2 * row] = i0; tok_idx[2 * row + 1] = i1;
    tok_w[2 * row] = w0; tok_w[2 * row + 1] = w1;
    atomicAdd(&counts[i0], 1);
    atomicAdd(&counts[i1], 1);
  }
}

// ---------- routing ----------
__global__ void r_offsets_kernel(const int* __restrict__ counts, int* offsets, int* cursor) {
  if (threadIdx.x == 0) {
    int acc = 0;
    for (int e = 0; e < EE; ++e) { offsets[e] = acc; cursor[e] = acc; acc += counts[e]; }
  }
}
__global__ __launch_bounds__(256) void r_scatter_kernel(
    const int* __restrict__ tok_idx, const float* __restrict__ tok_w,
    int* cursor, int* __restrict__ perm, float* __restrict__ slotw,
    int* __restrict__ dest) {
  const int n = blockIdx.x * 256 + threadIdx.x;
  if (n >= NROW) return;
#pragma unroll
  for (int k = 0; k < 2; ++k) {
    const int e = tok_idx[2 * n + k];
    const int pos = atomicAdd(&cursor[e], 1);
    perm[pos] = n;
    slotw[pos] = tok_w[2 * n + k];
    dest[pos] = 2 * n + k;
  }
}

// ---------- MoE GEMM1: gathered xn2 @ w1[e] + b1 -> gelu -> hbuf ----------
__global__ __launch_bounds__(256) void gemm_moe1_kernel(
    const float* __restrict__ xn2, const float* __restrict__ w1,
    const float* __restrict__ b1, const int* __restrict__ perm,
    const int* __restrict__ offsets, const int* __restrict__ counts,
    float* __restrict__ hbuf) {
  const int e = blockIdx.z;
  const int cnt = counts[e];
  const int m0 = blockIdx.y * 64;
  if (m0 >= cnt) return;
  const int n0 = blockIdx.x * 64;
  const int off = offsets[e];
  const float* Bw = w1 + (size_t)e * CC * FFD;
  __shared__ float As[16][68];
  __shared__ float Bs[16][64];
  const int tid = threadIdx.x, tx = tid & 15, ty = tid >> 4;
  const int akk = tid & 15, am = tid >> 4;
  const int bn = tid & 63, bk = tid >> 6;
  int rowg[4];
#pragma unroll
  for (int q = 0; q < 4; ++q) {
    int m = m0 + am + 16 * q;
    rowg[q] = perm[off + (m < cnt ? m : cnt - 1)];
  }
  float acc[4][4] = {};
  for (int k0 = 0; k0 < CC; k0 += 16) {
#pragma unroll
    for (int q = 0; q < 4; ++q) {
      As[akk][am + 16 * q] = xn2[(size_t)rowg[q] * CC + k0 + akk];
      Bs[bk + 4 * q][bn] = Bw[(size_t)(k0 + bk + 4 * q) * FFD + n0 + bn];
    }
    __syncthreads();
#pragma unroll
    for (int kk = 0; kk < 16; ++kk) {
      const float4 av = *(const float4*)&As[kk][ty * 4];
      const float4 bv = *(const float4*)&Bs[kk][tx * 4];
      const float aa[4] = {av.x, av.y, av.z, av.w};
      const float bb4[4] = {bv.x, bv.y, bv.z, bv.w};
#pragma unroll
      for (int i = 0; i < 4; ++i)
#pragma unroll
        for (int jj = 0; jj < 4; ++jj) acc[i][jj] += aa[i] * bb4[jj];
    }
    __syncthreads();
  }
#pragma unroll
  for (int i = 0; i < 4; ++i) {
    const int mr = m0 + ty * 4 + i;
    if (mr < cnt) {
#pragma unroll
      for (int jj = 0; jj < 4; ++jj) {
        const int c = n0 + tx * 4 + jj;
        const float t = acc[i][jj] + b1[e * FFD + c];
        const float gel = 0.5f * t * (1.0f + erff(t * 0.70710678118654752f));
        hbuf[(size_t)(off + mr) * FFD + c] = gel;
      }
    }
  }
}

// ---------- MoE GEMM2: hbuf @ w2[e] + b2 -> *w -> slot_out ----------
__global__ __launch_bounds__(256) void gemm_moe2_kernel(
    const float* __restrict__ hbuf, const float* __restrict__ w2,
    const float* __restrict__ b2, const int* __restrict__ offsets,
    const int* __restrict__ counts, const int* __restrict__ dest,
    const float* __restrict__ slotw, float* __restrict__ so) {
  const int e = blockIdx.z;
  const int cnt = counts[e];
  const int m0 = blockIdx.y * 64;
  if (m0 >= cnt) return;
  const int n0 = blockIdx.x * 64;
  const int off = offsets[e];
  const float* Bw = w2 + (size_t)e * FFD * CC;
  __shared__ float As[16][68];
  __shared__ float Bs[16][64];
  const int tid = threadIdx.x, tx = tid & 15, ty = tid >> 4;
  const int akk = tid & 15, am = tid >> 4;
  const int bn = tid & 63, bk = tid >> 6;
  int rowg[4];
#pragma unroll
  for (int q = 0; q < 4; ++q) {
    int m = m0 + am + 16 * q;
    rowg[q] = off + (m < cnt ? m : cnt - 1);
  }
  float acc[4][4] = {};
  for (int k0 = 0; k0 < FFD; k0 += 16) {
#pragma unroll
    for (int q = 0; q < 4; ++q) {
      As[akk][am + 16 * q] = hbuf[(size_t)rowg[q] * FFD + k0 + akk];
      Bs[bk + 4 * q][bn] = Bw[(size_t)(k0 + bk + 4 * q) * CC + n0 + bn];
    }
    __syncthreads();
#pragma unroll
    for (int kk = 0; kk < 16; ++kk) {
      const float4 av = *(const float4*)&As[kk][ty * 4];
      const float4 bv = *(const float4*)&Bs[kk][tx * 4];
      const float aa[4] = {av.x, av.y, av.z, av.w};
      const float bb4[4] = {bv.x, bv.y, bv.z, bv.w};
#pragma unroll
      for (int i = 0; i < 4; ++i)
#pragma unroll
        for (int jj = 0; jj < 4; ++jj) acc[i][jj] += aa[i] * bb4[jj];
    }
    __syncthreads();
  }
#pragma unroll
  for (int i = 0; i < 4; ++i) {
    const int mr = m0 + ty * 4 + i;
    if (mr < cnt) {
      const int sIdx = off + mr;
      const int dd = dest[sIdx];
      const float wv = slotw[sIdx];
#pragma unroll
      for (int jj = 0; jj < 4; ++jj) {
        const int c = n0 + tx * 4 + jj;
        so[(size_t)dd * CC + c] = wv * (acc[i][jj] + b2[e * CC + c]);
      }
    }
  }
}

// ---------- final: out = h + slot0 + slot1 ----------
__global__ __launch_bounds__(256) void final_kernel(
    const float* __restrict__ h, const float* __restrict__ so,
    float* __restrict__ out) {
  const int i = blockIdx.x * 256 + threadIdx.x;  // float4 index, NROW*96
  const int n = i / 96, c = i - n * 96;
  const float4* h4 = (const float4*)h;
  const float4* s4 = (const float4*)so;
  float4* o4 = (float4*)out;
  const float4 a = h4[i];
  const float4 b0 = s4[(size_t)n * 192 + c];
  const float4 b1 = s4[(size_t)n * 192 + 96 + c];
  o4[i] = make_float4(a.x + b0.x + b1.x, a.y + b0.y + b1.y,
                      a.z + b0.z + b1.z, a.w + b0.w + b1.w);
}

// ---------- host ----------
// Workspace layout (lifetime-aliased; ~41 MB total):
//   region A [0, 3 MiB):        xn (live ln->qkv_gemm)  ALIAS yat (attn->hbs)
//   region B [A, A+24 MiB):     qkv|qr|kr|qp|kp (live ->attn)  ALIAS hmid (moe1->moe2)
//   then: hbufr, xn2, so, routing arrays.
extern "C" void kernel_launch(void* const* d_in, const int* in_sizes, int n_in,
                              void* d_out, int out_size, void* d_ws, size_t ws_size,
                              hipStream_t stream) {
  const float* x          = (const float*)d_in[0];
  const float* ln1_g      = (const float*)d_in[1];
  const float* ln1_b      = (const float*)d_in[2];
  const float* ln2_g      = (const float*)d_in[3];
  const float* ln2_b      = (const float*)d_in[4];
  const float* qkv_w      = (const float*)d_in[5];
  const float* qkv_b      = (const float*)d_in[6];
  const float* pre_g      = (const float*)d_in[7];
  const float* pre_b      = (const float*)d_in[8];
  const float* blocks     = (const float*)d_in[9];
  const float* wrow       = (const float*)d_in[10];
  const float* wcol       = (const float*)d_in[11];
  const float* alpha      = (const float*)d_in[12];
  const float* biasv      = (const float*)d_in[13];
  const float* ang        = (const float*)d_in[14];
  const float* anb        = (const float*)d_in[15];
  const float* outg       = (const float*)d_in[16];
  const float* outb       = (const float*)d_in[17];
  const float* fg         = (const float*)d_in[18];
  const float* gatew      = (const float*)d_in[19];
  const float* w1         = (const float*)d_in[20];
  const float* b1         = (const float*)d_in[21];
  const float* w2         = (const float*)d_in[22];
  const float* b2         = (const float*)d_in[23];
  float* out = (float*)d_out;

  char* ws = (char*)d_ws;
  constexpr size_t SZ_ROWC  = (size_t)NROW * CC * 4;          // 3,145,728
  constexpr size_t SZ_QKV   = (size_t)NROW * QKVN * 4;        // 9,437,184
  constexpr size_t SZ_HEAD  = (size_t)BB * HH * TT * DD * 4;  // 3,145,728
  constexpr size_t SZ_HMID  = (size_t)NSLOT * FFD * 4;        // 25,165,824
  constexpr size_t OFF_A    = 0;                               // xn / yat
  constexpr size_t OFF_B    = OFF_A + SZ_ROWC;                 // qkv.. / hmid
  constexpr size_t OFF_QR   = OFF_B + SZ_QKV;
  constexpr size_t OFF_KR   = OFF_QR + SZ_HEAD;
  constexpr size_t OFF_QP   = OFF_KR + SZ_HEAD;
  constexpr size_t OFF_KP   = OFF_QP + SZ_HEAD;
  // qkv..kp = 22,020,096 B; hmid needs 25,165,824 B; the extra 3,145,728
  // spills into the region after kp, which is dead by the time moe1 runs.
  constexpr size_t OFF_HB   = OFF_B + SZ_HMID;                 // hbufr
  constexpr size_t OFF_XN2  = OFF_HB + SZ_ROWC;
  constexpr size_t OFF_SO   = OFF_XN2 + SZ_ROWC;
  constexpr size_t OFF_TI   = OFF_SO + (size_t)NSLOT * CC * 4;
  constexpr size_t OFF_TW   = OFF_TI + NSLOT * 4;
  constexpr size_t OFF_PERM = OFF_TW + NSLOT * 4;
  constexpr size_t OFF_SW   = OFF_PERM + NSLOT * 4;
  constexpr size_t OFF_DEST = OFF_SW + NSLOT * 4;
  constexpr size_t OFF_CNT  = OFF_DEST + NSLOT * 4;
  constexpr size_t OFF_OFFS = OFF_CNT + 256;
  constexpr size_t OFF_CUR  = OFF_OFFS + 256;

  float* xn    = (float*)(ws + OFF_A);
  float* yat   = (float*)(ws + OFF_A);     // alias: xn dead after gemm_qkv
  float* qkv   = (float*)(ws + OFF_B);
  float* qr    = (float*)(ws + OFF_QR);
  float* kr    = (float*)(ws + OFF_KR);
  float* qp    = (float*)(ws + OFF_QP);
  float* kp    = (float*)(ws + OFF_KP);
  float* hmid  = (float*)(ws + OFF_B);     // alias: qkv..kp dead after attn
  float* hbufr = (float*)(ws + OFF_HB);
  float* xn2   = (float*)(ws + OFF_XN2);
  float* so    = (float*)(ws + OFF_SO);
  int*   tok_idx = (int*)(ws + OFF_TI);
  float* tok_w   = (float*)(ws + OFF_TW);
  int*   perm    = (int*)(ws + OFF_PERM);
  float* slotw   = (float*)(ws + OFF_SW);
  int*   dest    = (int*)(ws + OFF_DEST);
  int*   counts  = (int*)(ws + OFF_CNT);
  int*   offsets = (int*)(ws + OFF_OFFS);
  int*   cursor  = (int*)(ws + OFF_CUR);

  zero_counts_kernel<<<1, 64, 0, stream>>>(counts);
  ln_row_kernel<<<NROW, 64, 0, stream>>>(x, ln1_g, ln1_b, xn);
  gemm_qkv_kernel<<<dim3(QKVN / 64, NROW / 64), 256, 0, stream>>>(xn, qkv_w, qkv_b, qkv);
  rope_kernel<<<(BB * HH * TT * 48) / 256, 256, 0, stream>>>(qkv, qr, kr, qp, kp);
  attn_kernel<<<dim3(TT / 32, BB * HH), 256, 0, stream>>>(qr, kr, qp, kp, qkv, ang, anb, fg, yat);
  hbs_kernel<<<NROW, 128, 0, stream>>>(yat, x, outg, outb, pre_g, pre_b, blocks,
                                       wrow, wcol, alpha, biasv, ln2_g, ln2_b,
                                       gatew, hbufr, xn2, tok_idx, tok_w, counts);
  r_offsets_kernel<<<1, 64, 0, stream>>>(counts, offsets, cursor);
  r_scatter_kernel<<<NROW / 256, 256, 0, stream>>>(tok_idx, tok_w, cursor, perm, slotw, dest);
  gemm_moe1_kernel<<<dim3(FFD / 64, NROW / 64, EE), 256, 0, stream>>>(
      xn2, w1, b1, perm, offsets, counts, hmid);
  gemm_moe2_kernel<<<dim3(CC / 64, NROW / 64, EE), 256, 0, stream>>>(
      hmid, w2, b2, offsets, counts, dest, slotw, so);
  final_kernel<<<(NROW * CC / 4) / 256, 256, 0, stream>>>(hbufr, so, out);
}

// Round 4
// 626.146 us; speedup vs baseline: 2.7712x; 2.7712x over previous
//
#include <hip/hip_runtime.h>
#include <math.h>

#define BB 2
#define TT 1024
#define CC 384
#define HH 4
#define DD 96
#define EE 8
#define FFD 1536
#define NROW (BB*TT)
#define QKVN (3*CC)
#define NSLOT (NROW*2)

// ---------- helpers ----------
__device__ __forceinline__ float wredSum64(float v) {
#pragma unroll
  for (int o = 32; o > 0; o >>= 1) v += __shfl_xor(v, o, 64);
  return v;
}
__device__ __forceinline__ float rsum16(float v) {
#pragma unroll
  for (int o = 8; o > 0; o >>= 1) v += __shfl_xor(v, o, 16);
  return v;
}
__device__ __forceinline__ float rmax16(float v) {
#pragma unroll
  for (int o = 8; o > 0; o >>= 1) v = fmaxf(v, __shfl_xor(v, o, 16));
  return v;
}
__device__ __forceinline__ float dot4f(const float4 a, const float4 b) {
  return a.x*b.x + a.y*b.y + a.z*b.z + a.w*b.w;
}
__device__ __forceinline__ float blockRed128(float v, float* red) {
  v = wredSum64(v);
  const int w = threadIdx.x >> 6;
  if ((threadIdx.x & 63) == 0) red[w] = v;
  __syncthreads();
  float r = red[0] + red[1];
  __syncthreads();
  return r;
}
__device__ __forceinline__ float elup1(float x) {  // elu(x)+1
  return x > 0.f ? x + 1.f : expf(x);
}

// ---------- kernel: zero routing counters ----------
__global__ void zero_counts_kernel(int* counts) {
  if (threadIdx.x < EE) counts[threadIdx.x] = 0;
}

// ---------- kernel: LayerNorm over C (one wave per row) ----------
__global__ __launch_bounds__(64) void ln_row_kernel(
    const float* __restrict__ xin, const float* __restrict__ g,
    const float* __restrict__ b, float* __restrict__ xout) {
  const int row = blockIdx.x;
  const int lane = threadIdx.x;
  const size_t base = (size_t)row * CC;
  float v[6];
#pragma unroll
  for (int p = 0; p < 6; ++p) v[p] = xin[base + lane + 64 * p];
  float s = v[0] + v[1] + v[2] + v[3] + v[4] + v[5];
  s = wredSum64(s);
  const float mu = s * (1.f / CC);
  float sq = 0.f;
#pragma unroll
  for (int p = 0; p < 6; ++p) { float d = v[p] - mu; sq += d * d; }
  sq = wredSum64(sq);
  const float rinv = rsqrtf(sq * (1.f / CC) + 1e-5f);
#pragma unroll
  for (int p = 0; p < 6; ++p) {
    const int c = lane + 64 * p;
    xout[base + c] = (v[p] - mu) * rinv * g[c] + b[c];
  }
}

// ---------- kernel: QKV GEMM 2048x1152x384 (fp32, tiled) ----------
__global__ __launch_bounds__(256) void gemm_qkv_kernel(
    const float* __restrict__ A, const float* __restrict__ Bw,
    const float* __restrict__ bias, float* __restrict__ Cout) {
  const int N = QKVN, K = CC;
  const int n0 = blockIdx.x * 64, m0 = blockIdx.y * 64;
  __shared__ float As[16][68];
  __shared__ float Bs[16][64];
  const int tid = threadIdx.x, tx = tid & 15, ty = tid >> 4;
  const int akk = tid & 15, am = tid >> 4;
  const int bn = tid & 63, bk = tid >> 6;
  float acc[4][4] = {};
  for (int k0 = 0; k0 < K; k0 += 16) {
#pragma unroll
    for (int q = 0; q < 4; ++q) {
      As[akk][am + 16 * q] = A[(size_t)(m0 + am + 16 * q) * K + k0 + akk];
      Bs[bk + 4 * q][bn] = Bw[(size_t)(k0 + bk + 4 * q) * N + n0 + bn];
    }
    __syncthreads();
#pragma unroll
    for (int kk = 0; kk < 16; ++kk) {
      const float4 av = *(const float4*)&As[kk][ty * 4];
      const float4 bv = *(const float4*)&Bs[kk][tx * 4];
      const float aa[4] = {av.x, av.y, av.z, av.w};
      const float bb4[4] = {bv.x, bv.y, bv.z, bv.w};
#pragma unroll
      for (int i = 0; i < 4; ++i)
#pragma unroll
        for (int jj = 0; jj < 4; ++jj) acc[i][jj] += aa[i] * bb4[jj];
    }
    __syncthreads();
  }
#pragma unroll
  for (int i = 0; i < 4; ++i) {
    const int r = m0 + ty * 4 + i;
#pragma unroll
    for (int jj = 0; jj < 4; ++jj) {
      const int c = n0 + tx * 4 + jj;
      Cout[(size_t)r * N + c] = acc[i][jj] + bias[c];
    }
  }
}

// ---------- kernel: RoPE + elu+1 features ----------
__global__ __launch_bounds__(256) void rope_kernel(
    const float* __restrict__ qkv, float* __restrict__ qr, float* __restrict__ kr,
    float* __restrict__ qp, float* __restrict__ kp) {
  const int gid = blockIdx.x * 256 + threadIdx.x;  // B*H*T*48
  const int i = gid % 48;
  const int t = (gid / 48) % TT;
  const int h = (gid / (48 * TT)) % HH;
  const int b = gid / (48 * TT * HH);
  const float inv = 1.0f / powf(10000.0f, (float)i * (1.0f / 48.0f));
  const float ang = (float)t * inv;
  float sn, cs;
  sincosf(ang, &sn, &cs);
  const float* row = qkv + ((size_t)(b * TT + t)) * QKVN + h * DD;
  const float q1 = row[i], q2 = row[i + 48];
  const float k1 = row[CC + i], k2 = row[CC + i + 48];
  const float qo1 = q1 * cs - q2 * sn, qo2 = q2 * cs + q1 * sn;
  const float ko1 = k1 * cs - k2 * sn, ko2 = k2 * cs + k1 * sn;
  const size_t ob = ((size_t)((b * HH + h) * TT + t)) * DD;
  qr[ob + i] = qo1; qr[ob + i + 48] = qo2;
  kr[ob + i] = ko1; kr[ob + i + 48] = ko2;
  const float scale = 0.10206207261596577f;  // 1/sqrt(96)
  qp[ob + i] = elup1(qo1 * scale); qp[ob + i + 48] = elup1(qo2 * scale);
  kp[ob + i] = elup1(ko1 * scale); kp[ob + i + 48] = elup1(ko2 * scale);
}

// ---------- kernel: fused dual attention (sharp softmax + linear) ----------
// v3: v2's balanced pairing (tiles k and 63-k per block, constant 33 chunks)
// but race-proof LDS: dedicated Vt tile (no Kt reuse), barrier at top AND
// bottom of the side loop, stage->bar->scores->bar->PV->bar per chunk.
// Every shared buffer has a full barrier between last-read and next-write.
__global__ __launch_bounds__(256, 2) void attn_kernel(
    const float* __restrict__ qr, const float* __restrict__ kr,
    const float* __restrict__ qp, const float* __restrict__ kp,
    const float* __restrict__ qkv, const float* __restrict__ ang,
    const float* __restrict__ anb, const float* __restrict__ fgp,
    float* __restrict__ y_attn) {
  __shared__ float Qt[16][100];    // pitch 100: avoid 96%32==0 4-way conflict
  __shared__ float Qpt[16][100];
  __shared__ float Kt[32][100];
  __shared__ float Kpt[32][100];
  __shared__ float Vt[32][100];
  __shared__ float Ps[16][34];
  __shared__ float Pl[16][34];
  const int bh = blockIdx.y, b = bh >> 2, h = bh & 3;
  const int pk = blockIdx.x;                 // pair id 0..31
  const int tid = threadIdx.x, j = tid & 15, rg = tid >> 4;
  const float a = 1.f / (1.f + expf(-fgp[0]));
#pragma unroll 1
  for (int side = 0; side < 2; ++side) {
    const int qt = side ? (63 - pk) : pk;    // tiles k and 63-k
    const int t0 = qt << 4;
    const int t = t0 + rg;                   // this thread's query row
    const size_t qbase = ((size_t)bh * TT + t0) * DD;
    __syncthreads();                         // nothing may still read Qt/Qpt
#pragma unroll
    for (int p = 0; p < 6; ++p) {            // 16x96 = 1536 floats
      const int i = tid + 256 * p, r = i / 96, d = i - r * 96;
      Qt[r][d] = qr[qbase + i];
      Qpt[r][d] = qp[qbase + i];
    }
    float accS[6] = {}, accN[6] = {};
    float mrow = -1e30f, lrow = 0.f, den = 0.f;
    const int nc = (qt >> 1) + 1;            // s-chunks of 32 for this tile
    __syncthreads();
    for (int c = 0; c < nc; ++c) {
      const int s0 = c << 5;
      const float* vb = qkv + ((size_t)(b * TT + s0)) * QKVN + 2 * CC + h * DD;
      const size_t kb = ((size_t)bh * TT + s0) * DD;
#pragma unroll
      for (int p = 0; p < 12; ++p) {         // stage K, Kp, V (32x96 each)
        const int i = tid + 256 * p, s = i / 96, d = i - s * 96;
        Kt[s][d] = kr[kb + i];
        Kpt[s][d] = kp[kb + i];
        Vt[s][d] = vb[(size_t)s * QKVN + d];
      }
      __syncthreads();                       // stage complete
      float ds0 = 0.f, ds1 = 0.f, dl0 = 0.f, dl1 = 0.f;
#pragma unroll
      for (int dd = 0; dd < 96; dd += 4) {
        const float4 qa = *(const float4*)&Qt[rg][dd];
        const float4 ka = *(const float4*)&Kt[j][dd];
        const float4 k2 = *(const float4*)&Kt[j + 16][dd];
        ds0 += dot4f(qa, ka); ds1 += dot4f(qa, k2);
        const float4 pa = *(const float4*)&Qpt[rg][dd];
        const float4 fa = *(const float4*)&Kpt[j][dd];
        const float4 f2 = *(const float4*)&Kpt[j + 16][dd];
        dl0 += dot4f(pa, fa); dl1 += dot4f(pa, f2);
      }
      const float scale = 0.10206207261596577f;
      float sc0 = ds0 * scale, sc1 = ds1 * scale;
      if (c == nc - 1) {                     // diagonal chunk: mask s > t
        if (s0 + j > t)      { sc0 = -1e30f; dl0 = 0.f; }
        if (s0 + j + 16 > t) { sc1 = -1e30f; dl1 = 0.f; }
      }
      // online softmax (sharp) + linear accumulate for row rg
      const float cm = rmax16(fmaxf(sc0, sc1));
      const float mn = fmaxf(mrow, cm);
      const float sf = expf(mrow - mn);
      const float p0 = expf(sc0 - mn), p1 = expf(sc1 - mn);
      lrow = lrow * sf + rsum16(p0 + p1);
      mrow = mn;
      den += rsum16(dl0 + dl1);
#pragma unroll
      for (int u = 0; u < 6; ++u) accS[u] *= sf;
      Ps[rg][j] = p0; Ps[rg][j + 16] = p1;
      Pl[rg][j] = dl0; Pl[rg][j + 16] = dl1;
      __syncthreads();                       // scores done; Ps/Pl visible
      const int c0 = j * 6;                  // this thread's 6 output cols
#pragma unroll
      for (int s = 0; s < 32; s += 2) {
        const float2 pA = *(const float2*)&Ps[rg][s];
        const float2 lA = *(const float2*)&Pl[rg][s];
        const float* v0p = &Vt[s][c0];
        const float* v1p = v0p + 100;
        float va[6], vb2[6];
        *(float2*)&va[0] = *(const float2*)(v0p);
        *(float2*)&va[2] = *(const float2*)(v0p + 2);
        *(float2*)&va[4] = *(const float2*)(v0p + 4);
        *(float2*)&vb2[0] = *(const float2*)(v1p);
        *(float2*)&vb2[2] = *(const float2*)(v1p + 2);
        *(float2*)&vb2[4] = *(const float2*)(v1p + 4);
#pragma unroll
        for (int u = 0; u < 6; ++u) {
          accS[u] += pA.x * va[u] + pA.y * vb2[u];
          accN[u] += lA.x * va[u] + lA.y * vb2[u];
        }
      }
      __syncthreads();                       // PV done before next stage
    }
    // epilogue: normalize, LN(y_lin) over D=96, gated combine
    const float invl = 1.0f / lrow;
    const float dinv = 1.0f / (den + 1e-4f);
    float yl[6];
    float s1 = 0.f;
#pragma unroll
    for (int u = 0; u < 6; ++u) { yl[u] = accN[u] * dinv; s1 += yl[u]; }
    s1 = rsum16(s1);
    const float mu = s1 * (1.f / DD);
    float s2 = 0.f;
#pragma unroll
    for (int u = 0; u < 6; ++u) { const float d = yl[u] - mu; s2 += d * d; }
    s2 = rsum16(s2);
    const float rr = rsqrtf(s2 * (1.f / DD) + 1e-5f);
    const size_t ob = ((size_t)(b * TT + t)) * CC + h * DD + j * 6;
#pragma unroll
    for (int u = 0; u < 6; ++u) {
      const float ylin = (yl[u] - mu) * rr * ang[j * 6 + u] + anb[j * 6 + u];
      const float ys = accS[u] * invl;
      y_attn[ob + u] = a * ys + (1.f - a) * ylin;
    }
  }
}

// ---------- kernel: out-LN + HBS + residual + LN2 + gate top-2 ----------
__global__ __launch_bounds__(128) void hbs_kernel(
    const float* __restrict__ y_attn, const float* __restrict__ x,
    const float* __restrict__ outg, const float* __restrict__ outb,
    const float* __restrict__ preg, const float* __restrict__ preb,
    const float* __restrict__ blocks, const float* __restrict__ wrow,
    const float* __restrict__ wcol, const float* __restrict__ alphap,
    const float* __restrict__ biasv, const float* __restrict__ ln2g,
    const float* __restrict__ ln2b, const float* __restrict__ gatew,
    float* __restrict__ hout, float* __restrict__ xn2,
    int* __restrict__ tok_idx, float* __restrict__ tok_w, int* __restrict__ counts) {
  __shared__ float flatS[CC];
  __shared__ float ybuf[CC];
  __shared__ float xbuf[CC];
  __shared__ float tmp[400];
  __shared__ float red[2];
  __shared__ float logit[EE];
  const int row = blockIdx.x, tid = threadIdx.x;
  const size_t base = (size_t)row * CC;
  float v[3];
#pragma unroll
  for (int p = 0; p < 3; ++p) v[p] = y_attn[base + tid + 128 * p];
  // LN(out_norm)
  float s = blockRed128(v[0] + v[1] + v[2], red);
  float mu = s * (1.f / CC);
  float sq = 0.f;
#pragma unroll
  for (int p = 0; p < 3; ++p) { const float d = v[p] - mu; sq += d * d; }
  sq = blockRed128(sq, red);
  float rin = rsqrtf(sq * (1.f / CC) + 1e-5f);
  float w[3];
#pragma unroll
  for (int p = 0; p < 3; ++p) {
    const int c = tid + 128 * p;
    w[p] = (v[p] - mu) * rin * outg[c] + outb[c];
  }
  // LN(pre)
  s = blockRed128(w[0] + w[1] + w[2], red);
  mu = s * (1.f / CC);
  sq = 0.f;
#pragma unroll
  for (int p = 0; p < 3; ++p) { const float d = w[p] - mu; sq += d * d; }
  sq = blockRed128(sq, red);
  rin = rsqrtf(sq * (1.f / CC) + 1e-5f);
#pragma unroll
  for (int p = 0; p < 3; ++p) {
    const int c = tid + 128 * p;
    flatS[c] = (w[p] - mu) * rin * preg[c] + preb[c];
  }
  __syncthreads();
  // block mixing: y[g,c] = sum_b flat[g*16+b]*blocks[g,b,c]
#pragma unroll
  for (int p = 0; p < 3; ++p) {
    const int o = tid + 128 * p;
    const int g = o >> 4, cc = o & 15;
    const float* bp = blocks + g * 256 + cc;
    const float* fp = flatS + g * 16;
    float acc = 0.f;
#pragma unroll
    for (int bb = 0; bb < 16; ++bb) acc += fp[bb] * bp[bb * 16];
    ybuf[o] = acc;
  }
  // monarch stage 1: tmp[i,k] = sum_j grid[i,j]*wcol[j,k]
#pragma unroll
  for (int p = 0; p < 4; ++p) {
    const int o = tid + 128 * p;
    if (o < 400) {
      const int i = o / 20, k = o - i * 20;
      float acc = 0.f;
#pragma unroll
      for (int jj = 0; jj < 20; ++jj) {
        const int src = i * 20 + jj;
        const float gv = (src < CC) ? flatS[src] : 0.f;
        acc += gv * wcol[jj * 20 + k];
      }
      tmp[o] = acc;
    }
  }
  __syncthreads();
  const float alpha = alphap[0];
  float hr[3];
#pragma unroll
  for (int p = 0; p < 3; ++p) {
    const int o = tid + 128 * p;
    const int i = o / 20, ll = o - i * 20;
    float mon = 0.f;
#pragma unroll
    for (int k = 0; k < 20; ++k) mon += tmp[i * 20 + k] * wrow[ll * 20 + k];
    const float hb = ybuf[383 - o] + alpha * mon + biasv[o];
    const float hv = x[base + o] + hb;
    hout[base + o] = hv;
    hr[p] = hv;
  }
  // LN2
  s = blockRed128(hr[0] + hr[1] + hr[2], red);
  mu = s * (1.f / CC);
  sq = 0.f;
#pragma unroll
  for (int p = 0; p < 3; ++p) { const float d = hr[p] - mu; sq += d * d; }
  sq = blockRed128(sq, red);
  rin = rsqrtf(sq * (1.f / CC) + 1e-5f);
#pragma unroll
  for (int p = 0; p < 3; ++p) {
    const int c = tid + 128 * p;
    const float xv = (hr[p] - mu) * rin * ln2g[c] + ln2b[c];
    xn2[base + c] = xv;
    xbuf[c] = xv;
  }
  __syncthreads();
  // gate logits
  const int e = tid >> 4, jj = tid & 15;
  float part = 0.f;
  for (int c = jj; c < CC; c += 16) part += xbuf[c] * gatew[c * EE + e];
  part = rsum16(part);
  if (jj == 0) logit[e] = fminf(20.f, fmaxf(-20.f, part));
  __syncthreads();
  if (tid == 0) {
    float lg[EE];
#pragma unroll
    for (int ee = 0; ee < EE; ++ee) lg[ee] = logit[ee];
    int i0 = 0; float v0 = lg[0];
#pragma unroll
    for (int ee = 1; ee < EE; ++ee) if (lg[ee] > v0) { v0 = lg[ee]; i0 = ee; }
    int i1 = -1; float v1 = -1e30f;
#pragma unroll
    for (int ee = 0; ee < EE; ++ee)
      if (ee != i0 && lg[ee] > v1) { v1 = lg[ee]; i1 = ee; }
    const float e1 = expf(v1 - v0);
    const float w0 = 1.f / (1.f + e1), w1 = e1 / (1.f + e1);
    tok_idx[2 * row] = i0; tok_idx[2 * row + 1] = i1;
    tok_w[2 * row] = w0; tok_w[2 * row + 1] = w1;
    atomicAdd(&counts[i0], 1);
    atomicAdd(&counts[i1], 1);
  }
}

// ---------- routing ----------
__global__ void r_offsets_kernel(const int* __restrict__ counts, int* offsets, int* cursor) {
  if (threadIdx.x == 0) {
    int acc = 0;
    for (int e = 0; e < EE; ++e) { offsets[e] = acc; cursor[e] = acc; acc += counts[e]; }
  }
}
__global__ __launch_bounds__(256) void r_scatter_kernel(
    const int* __restrict__ tok_idx, const float* __restrict__ tok_w,
    int* cursor, int* __restrict__ perm, float* __restrict__ slotw,
    int* __restrict__ dest) {
  const int n = blockIdx.x * 256 + threadIdx.x;
  if (n >= NROW) return;
#pragma unroll
  for (int k = 0; k < 2; ++k) {
    const int e = tok_idx[2 * n + k];
    const int pos = atomicAdd(&cursor[e], 1);
    perm[pos] = n;
    slotw[pos] = tok_w[2 * n + k];
    dest[pos] = 2 * n + k;
  }
}

// ---------- MoE GEMM1: gathered xn2 @ w1[e] + b1 -> gelu -> hbuf ----------
__global__ __launch_bounds__(256) void gemm_moe1_kernel(
    const float* __restrict__ xn2, const float* __restrict__ w1,
    const float* __restrict__ b1, const int* __restrict__ perm,
    const int* __restrict__ offsets, const int* __restrict__ counts,
    float* __restrict__ hbuf) {
  const int e = blockIdx.z;
  const int cnt = counts[e];
  const int m0 = blockIdx.y * 64;
  if (m0 >= cnt) return;
  const int n0 = blockIdx.x * 64;
  const int off = offsets[e];
  const float* Bw = w1 + (size_t)e * CC * FFD;
  __shared__ float As[16][68];
  __shared__ float Bs[16][64];
  const int tid = threadIdx.x, tx = tid & 15, ty = tid >> 4;
  const int akk = tid & 15, am = tid >> 4;
  const int bn = tid & 63, bk = tid >> 6;
  int rowg[4];
#pragma unroll
  for (int q = 0; q < 4; ++q) {
    int m = m0 + am + 16 * q;
    rowg[q] = perm[off + (m < cnt ? m : cnt - 1)];
  }
  float acc[4][4] = {};
  for (int k0 = 0; k0 < CC; k0 += 16) {
#pragma unroll
    for (int q = 0; q < 4; ++q) {
      As[akk][am + 16 * q] = xn2[(size_t)rowg[q] * CC + k0 + akk];
      Bs[bk + 4 * q][bn] = Bw[(size_t)(k0 + bk + 4 * q) * FFD + n0 + bn];
    }
    __syncthreads();
#pragma unroll
    for (int kk = 0; kk < 16; ++kk) {
      const float4 av = *(const float4*)&As[kk][ty * 4];
      const float4 bv = *(const float4*)&Bs[kk][tx * 4];
      const float aa[4] = {av.x, av.y, av.z, av.w};
      const float bb4[4] = {bv.x, bv.y, bv.z, bv.w};
#pragma unroll
      for (int i = 0; i < 4; ++i)
#pragma unroll
        for (int jj = 0; jj < 4; ++jj) acc[i][jj] += aa[i] * bb4[jj];
    }
    __syncthreads();
  }
#pragma unroll
  for (int i = 0; i < 4; ++i) {
    const int mr = m0 + ty * 4 + i;
    if (mr < cnt) {
#pragma unroll
      for (int jj = 0; jj < 4; ++jj) {
        const int c = n0 + tx * 4 + jj;
        const float t = acc[i][jj] + b1[e * FFD + c];
        const float gel = 0.5f * t * (1.0f + erff(t * 0.70710678118654752f));
        hbuf[(size_t)(off + mr) * FFD + c] = gel;
      }
    }
  }
}

// ---------- MoE GEMM2: hbuf @ w2[e] + b2 -> *w -> slot_out ----------
__global__ __launch_bounds__(256) void gemm_moe2_kernel(
    const float* __restrict__ hbuf, const float* __restrict__ w2,
    const float* __restrict__ b2, const int* __restrict__ offsets,
    const int* __restrict__ counts, const int* __restrict__ dest,
    const float* __restrict__ slotw, float* __restrict__ so) {
  const int e = blockIdx.z;
  const int cnt = counts[e];
  const int m0 = blockIdx.y * 64;
  if (m0 >= cnt) return;
  const int n0 = blockIdx.x * 64;
  const int off = offsets[e];
  const float* Bw = w2 + (size_t)e * FFD * CC;
  __shared__ float As[16][68];
  __shared__ float Bs[16][64];
  const int tid = threadIdx.x, tx = tid & 15, ty = tid >> 4;
  const int akk = tid & 15, am = tid >> 4;
  const int bn = tid & 63, bk = tid >> 6;
  int rowg[4];
#pragma unroll
  for (int q = 0; q < 4; ++q) {
    int m = m0 + am + 16 * q;
    rowg[q] = off + (m < cnt ? m : cnt - 1);
  }
  float acc[4][4] = {};
  for (int k0 = 0; k0 < FFD; k0 += 16) {
#pragma unroll
    for (int q = 0; q < 4; ++q) {
      As[akk][am + 16 * q] = hbuf[(size_t)rowg[q] * FFD + k0 + akk];
      Bs[bk + 4 * q][bn] = Bw[(size_t)(k0 + bk + 4 * q) * CC + n0 + bn];
    }
    __syncthreads();
#pragma unroll
    for (int kk = 0; kk < 16; ++kk) {
      const float4 av = *(const float4*)&As[kk][ty * 4];
      const float4 bv = *(const float4*)&Bs[kk][tx * 4];
      const float aa[4] = {av.x, av.y, av.z, av.w};
      const float bb4[4] = {bv.x, bv.y, bv.z, bv.w};
#pragma unroll
      for (int i = 0; i < 4; ++i)
#pragma unroll
        for (int jj = 0; jj < 4; ++jj) acc[i][jj] += aa[i] * bb4[jj];
    }
    __syncthreads();
  }
#pragma unroll
  for (int i = 0; i < 4; ++i) {
    const int mr = m0 + ty * 4 + i;
    if (mr < cnt) {
      const int sIdx = off + mr;
      const int dd = dest[sIdx];
      const float wv = slotw[sIdx];
#pragma unroll
      for (int jj = 0; jj < 4; ++jj) {
        const int c = n0 + tx * 4 + jj;
        so[(size_t)dd * CC + c] = wv * (acc[i][jj] + b2[e * CC + c]);
      }
    }
  }
}

// ---------- final: out = h + slot0 + slot1 ----------
__global__ __launch_bounds__(256) void final_kernel(
    const float* __restrict__ h, const float* __restrict__ so,
    float* __restrict__ out) {
  const int i = blockIdx.x * 256 + threadIdx.x;  // float4 index, NROW*96
  const int n = i / 96, c = i - n * 96;
  const float4* h4 = (const float4*)h;
  const float4* s4 = (const float4*)so;
  float4* o4 = (float4*)out;
  const float4 a = h4[i];
  const float4 b0 = s4[(size_t)n * 192 + c];
  const float4 b1 = s4[(size_t)n * 192 + 96 + c];
  o4[i] = make_float4(a.x + b0.x + b1.x, a.y + b0.y + b1.y,
                      a.z + b0.z + b1.z, a.w + b0.w + b1.w);
}

// ---------- host ----------
// Workspace layout (lifetime-aliased; ~41 MB total):
//   region A [0, 3 MiB):        xn (live ln->qkv_gemm)  ALIAS yat (attn->hbs)
//   region B [A, A+24 MiB):     qkv|qr|kr|qp|kp (live ->attn)  ALIAS hmid (moe1->moe2)
//   then: hbufr, xn2, so, routing arrays.
extern "C" void kernel_launch(void* const* d_in, const int* in_sizes, int n_in,
                              void* d_out, int out_size, void* d_ws, size_t ws_size,
                              hipStream_t stream) {
  const float* x          = (const float*)d_in[0];
  const float* ln1_g      = (const float*)d_in[1];
  const float* ln1_b      = (const float*)d_in[2];
  const float* ln2_g      = (const float*)d_in[3];
  const float* ln2_b      = (const float*)d_in[4];
  const float* qkv_w      = (const float*)d_in[5];
  const float* qkv_b      = (const float*)d_in[6];
  const float* pre_g      = (const float*)d_in[7];
  const float* pre_b      = (const float*)d_in[8];
  const float* blocks     = (const float*)d_in[9];
  const float* wrow       = (const float*)d_in[10];
  const float* wcol       = (const float*)d_in[11];
  const float* alpha      = (const float*)d_in[12];
  const float* biasv      = (const float*)d_in[13];
  const float* ang        = (const float*)d_in[14];
  const float* anb        = (const float*)d_in[15];
  const float* outg       = (const float*)d_in[16];
  const float* outb       = (const float*)d_in[17];
  const float* fg         = (const float*)d_in[18];
  const float* gatew      = (const float*)d_in[19];
  const float* w1         = (const float*)d_in[20];
  const float* b1         = (const float*)d_in[21];
  const float* w2         = (const float*)d_in[22];
  const float* b2         = (const float*)d_in[23];
  float* out = (float*)d_out;

  char* ws = (char*)d_ws;
  constexpr size_t SZ_ROWC  = (size_t)NROW * CC * 4;          // 3,145,728
  constexpr size_t SZ_QKV   = (size_t)NROW * QKVN * 4;        // 9,437,184
  constexpr size_t SZ_HEAD  = (size_t)BB * HH * TT * DD * 4;  // 3,145,728
  constexpr size_t SZ_HMID  = (size_t)NSLOT * FFD * 4;        // 25,165,824
  constexpr size_t OFF_A    = 0;                               // xn / yat
  constexpr size_t OFF_B    = OFF_A + SZ_ROWC;                 // qkv.. / hmid
  constexpr size_t OFF_QR   = OFF_B + SZ_QKV;
  constexpr size_t OFF_KR   = OFF_QR + SZ_HEAD;
  constexpr size_t OFF_QP   = OFF_KR + SZ_HEAD;
  constexpr size_t OFF_KP   = OFF_QP + SZ_HEAD;
  constexpr size_t OFF_HB   = OFF_B + SZ_HMID;                 // hbufr
  constexpr size_t OFF_XN2  = OFF_HB + SZ_ROWC;
  constexpr size_t OFF_SO   = OFF_XN2 + SZ_ROWC;
  constexpr size_t OFF_TI   = OFF_SO + (size_t)NSLOT * CC * 4;
  constexpr size_t OFF_TW   = OFF_TI + NSLOT * 4;
  constexpr size_t OFF_PERM = OFF_TW + NSLOT * 4;
  constexpr size_t OFF_SW   = OFF_PERM + NSLOT * 4;
  constexpr size_t OFF_DEST = OFF_SW + NSLOT * 4;
  constexpr size_t OFF_CNT  = OFF_DEST + NSLOT * 4;
  constexpr size_t OFF_OFFS = OFF_CNT + 256;
  constexpr size_t OFF_CUR  = OFF_OFFS + 256;

  float* xn    = (float*)(ws + OFF_A);
  float* yat   = (float*)(ws + OFF_A);     // alias: xn dead after gemm_qkv
  float* qkv   = (float*)(ws + OFF_B);
  float* qr    = (float*)(ws + OFF_QR);
  float* kr    = (float*)(ws + OFF_KR);
  float* qp    = (float*)(ws + OFF_QP);
  float* kp    = (float*)(ws + OFF_KP);
  float* hmid  = (float*)(ws + OFF_B);     // alias: qkv..kp dead after attn
  float* hbufr = (float*)(ws + OFF_HB);
  float* xn2   = (float*)(ws + OFF_XN2);
  float* so    = (float*)(ws + OFF_SO);
  int*   tok_idx = (int*)(ws + OFF_TI);
  float* tok_w   = (float*)(ws + OFF_TW);
  int*   perm    = (int*)(ws + OFF_PERM);
  float* slotw   = (float*)(ws + OFF_SW);
  int*   dest    = (int*)(ws + OFF_DEST);
  int*   counts  = (int*)(ws + OFF_CNT);
  int*   offsets = (int*)(ws + OFF_OFFS);
  int*   cursor  = (int*)(ws + OFF_CUR);

  zero_counts_kernel<<<1, 64, 0, stream>>>(counts);
  ln_row_kernel<<<NROW, 64, 0, stream>>>(x, ln1_g, ln1_b, xn);
  gemm_qkv_kernel<<<dim3(QKVN / 64, NROW / 64), 256, 0, stream>>>(xn, qkv_w, qkv_b, qkv);
  rope_kernel<<<(BB * HH * TT * 48) / 256, 256, 0, stream>>>(qkv, qr, kr, qp, kp);
  attn_kernel<<<dim3(32, BB * HH), 256, 0, stream>>>(qr, kr, qp, kp, qkv, ang, anb, fg, yat);
  hbs_kernel<<<NROW, 128, 0, stream>>>(yat, x, outg, outb, pre_g, pre_b, blocks,
                                       wrow, wcol, alpha, biasv, ln2_g, ln2_b,
                                       gatew, hbufr, xn2, tok_idx, tok_w, counts);
  r_offsets_kernel<<<1, 64, 0, stream>>>(counts, offsets, cursor);
  r_scatter_kernel<<<NROW / 256, 256, 0, stream>>>(tok_idx, tok_w, cursor, perm, slotw, dest);
  gemm_moe1_kernel<<<dim3(FFD / 64, NROW / 64, EE), 256, 0, stream>>>(
      xn2, w1, b1, perm, offsets, counts, hmid);
  gemm_moe2_kernel<<<dim3(CC / 64, NROW / 64, EE), 256, 0, stream>>>(
      hmid, w2, b2, offsets, counts, dest, slotw, so);
  final_kernel<<<(NROW * CC / 4) / 256, 256, 0, stream>>>(hbufr, so, out);
}

// Round 7
// 481.055 us; speedup vs baseline: 3.6070x; 1.3016x over previous
//
#include <hip/hip_runtime.h>
#include <math.h>

#define BB 2
#define TT 1024
#define CC 384
#define HH 4
#define DD 96
#define EE 8
#define FFD 1536
#define NROW (BB*TT)
#define QKVN (3*CC)
#define NSLOT (NROW*2)

typedef float f32x4 __attribute__((ext_vector_type(4)));
typedef short bf16x8 __attribute__((ext_vector_type(8)));

// ---------- helpers ----------
__device__ __forceinline__ float wredSum64(float v) {
#pragma unroll
  for (int o = 32; o > 0; o >>= 1) v += __shfl_xor(v, o, 64);
  return v;
}
__device__ __forceinline__ float rsum16(float v) {
#pragma unroll
  for (int o = 8; o > 0; o >>= 1) v += __shfl_xor(v, o, 16);
  return v;
}
__device__ __forceinline__ float rmax16(float v) {
#pragma unroll
  for (int o = 8; o > 0; o >>= 1) v = fmaxf(v, __shfl_xor(v, o, 16));
  return v;
}
__device__ __forceinline__ float dot4f(const float4 a, const float4 b) {
  return a.x*b.x + a.y*b.y + a.z*b.z + a.w*b.w;
}
__device__ __forceinline__ float blockRed128(float v, float* red) {
  v = wredSum64(v);
  const int w = threadIdx.x >> 6;
  if ((threadIdx.x & 63) == 0) red[w] = v;
  __syncthreads();
  float r = red[0] + red[1];
  __syncthreads();
  return r;
}
__device__ __forceinline__ float elup1(float x) {  // elu(x)+1
  return x > 0.f ? x + 1.f : expf(x);
}
__device__ __forceinline__ unsigned short f2bf(float f) {  // RNE bf16
  unsigned int u = __float_as_uint(f);
  u = (u + 0x7FFFu + ((u >> 16) & 1u)) >> 16;
  return (unsigned short)u;
}

// ---------- kernel: zero routing counters ----------
__global__ void zero_counts_kernel(int* counts) {
  if (threadIdx.x < EE) counts[threadIdx.x] = 0;
}

// ---------- kernel: transpose + fp32->bf16 convert:  W[K][N] -> WT[N][K] ----------
__global__ __launch_bounds__(256) void transconv_kernel(
    const float* __restrict__ src, unsigned short* __restrict__ dst,
    int K, int N) {
  src += (size_t)blockIdx.z * K * N;
  dst += (size_t)blockIdx.z * K * N;
  const int k0 = blockIdx.y * 32, n0 = blockIdx.x * 32;
  __shared__ float tile[32][33];
  const int t = threadIdx.x;
  const int ki = t >> 3, nj = (t & 7) * 4;
  const float4 v = *(const float4*)&src[(size_t)(k0 + ki) * N + n0 + nj];
  tile[ki][nj] = v.x; tile[ki][nj + 1] = v.y;
  tile[ki][nj + 2] = v.z; tile[ki][nj + 3] = v.w;
  __syncthreads();
  const int ni = t >> 3, kj = (t & 7) * 4;
  ushort4 o;
  o.x = f2bf(tile[kj][ni]);     o.y = f2bf(tile[kj + 1][ni]);
  o.z = f2bf(tile[kj + 2][ni]); o.w = f2bf(tile[kj + 3][ni]);
  *(ushort4*)&dst[(size_t)(n0 + ni) * K + k0 + kj] = o;
}

// ---------- kernel: LayerNorm over C -> fp32 (one wave per row) ----------
// fp32 output: the routing decision (MoE top-2) is downstream of this path;
// bf16 here perturbs gate logits ~1e-3 and flips expert selection vs the
// fp32 reference (round-5 failure, absmax 0.358).
__global__ __launch_bounds__(64) void ln_row_kernel(
    const float* __restrict__ xin, const float* __restrict__ g,
    const float* __restrict__ b, float* __restrict__ xout) {
  const int row = blockIdx.x;
  const int lane = threadIdx.x;
  const size_t base = (size_t)row * CC;
  float v[6];
#pragma unroll
  for (int p = 0; p < 6; ++p) v[p] = xin[base + lane + 64 * p];
  float s = v[0] + v[1] + v[2] + v[3] + v[4] + v[5];
  s = wredSum64(s);
  const float mu = s * (1.f / CC);
  float sq = 0.f;
#pragma unroll
  for (int p = 0; p < 6; ++p) { float d = v[p] - mu; sq += d * d; }
  sq = wredSum64(sq);
  const float rinv = rsqrtf(sq * (1.f / CC) + 1e-5f);
#pragma unroll
  for (int p = 0; p < 6; ++p) {
    const int c = lane + 64 * p;
    xout[base + c] = (v[p] - mu) * rinv * g[c] + b[c];
  }
}

// ---------- kernel: QKV GEMM 2048x1152x384 (fp32, tiled) ----------
// Stays fp32: feeds attention -> hbs -> gate logits (routing-critical).
__global__ __launch_bounds__(256) void gemm_qkv_kernel(
    const float* __restrict__ A, const float* __restrict__ Bw,
    const float* __restrict__ bias, float* __restrict__ Cout) {
  const int N = QKVN, K = CC;
  const int n0 = blockIdx.x * 64, m0 = blockIdx.y * 64;
  __shared__ float As[16][68];
  __shared__ float Bs[16][64];
  const int tid = threadIdx.x, tx = tid & 15, ty = tid >> 4;
  const int akk = tid & 15, am = tid >> 4;
  const int bn = tid & 63, bk = tid >> 6;
  float acc[4][4] = {};
  for (int k0 = 0; k0 < K; k0 += 16) {
#pragma unroll
    for (int q = 0; q < 4; ++q) {
      As[akk][am + 16 * q] = A[(size_t)(m0 + am + 16 * q) * K + k0 + akk];
      Bs[bk + 4 * q][bn] = Bw[(size_t)(k0 + bk + 4 * q) * N + n0 + bn];
    }
    __syncthreads();
#pragma unroll
    for (int kk = 0; kk < 16; ++kk) {
      const float4 av = *(const float4*)&As[kk][ty * 4];
      const float4 bv = *(const float4*)&Bs[kk][tx * 4];
      const float aa[4] = {av.x, av.y, av.z, av.w};
      const float bb4[4] = {bv.x, bv.y, bv.z, bv.w};
#pragma unroll
      for (int i = 0; i < 4; ++i)
#pragma unroll
        for (int jj = 0; jj < 4; ++jj) acc[i][jj] += aa[i] * bb4[jj];
    }
    __syncthreads();
  }
#pragma unroll
  for (int i = 0; i < 4; ++i) {
    const int r = m0 + ty * 4 + i;
#pragma unroll
    for (int jj = 0; jj < 4; ++jj) {
      const int c = n0 + tx * 4 + jj;
      Cout[(size_t)r * N + c] = acc[i][jj] + bias[c];
    }
  }
}

// ---------- kernel: RoPE + elu+1 features ----------
__global__ __launch_bounds__(256) void rope_kernel(
    const float* __restrict__ qkv, float* __restrict__ qr, float* __restrict__ kr,
    float* __restrict__ qp, float* __restrict__ kp) {
  const int gid = blockIdx.x * 256 + threadIdx.x;  // B*H*T*48
  const int i = gid % 48;
  const int t = (gid / 48) % TT;
  const int h = (gid / (48 * TT)) % HH;
  const int b = gid / (48 * TT * HH);
  const float inv = 1.0f / powf(10000.0f, (float)i * (1.0f / 48.0f));
  const float ang = (float)t * inv;
  float sn, cs;
  sincosf(ang, &sn, &cs);
  const float* row = qkv + ((size_t)(b * TT + t)) * QKVN + h * DD;
  const float q1 = row[i], q2 = row[i + 48];
  const float k1 = row[CC + i], k2 = row[CC + i + 48];
  const float qo1 = q1 * cs - q2 * sn, qo2 = q2 * cs + q1 * sn;
  const float ko1 = k1 * cs - k2 * sn, ko2 = k2 * cs + k1 * sn;
  const size_t ob = ((size_t)((b * HH + h) * TT + t)) * DD;
  qr[ob + i] = qo1; qr[ob + i + 48] = qo2;
  kr[ob + i] = ko1; kr[ob + i + 48] = ko2;
  const float scale = 0.10206207261596577f;  // 1/sqrt(96)
  qp[ob + i] = elup1(qo1 * scale); qp[ob + i + 48] = elup1(qo2 * scale);
  kp[ob + i] = elup1(ko1 * scale); kp[ob + i + 48] = elup1(ko2 * scale);
}

// ---------- kernel: fused dual attention (sharp softmax + linear) ----------
// (unchanged from round-4 passing version)
__global__ __launch_bounds__(256, 2) void attn_kernel(
    const float* __restrict__ qr, const float* __restrict__ kr,
    const float* __restrict__ qp, const float* __restrict__ kp,
    const float* __restrict__ qkv, const float* __restrict__ ang,
    const float* __restrict__ anb, const float* __restrict__ fgp,
    float* __restrict__ y_attn) {
  __shared__ float Qt[16][100];
  __shared__ float Qpt[16][100];
  __shared__ float Kt[32][100];
  __shared__ float Kpt[32][100];
  __shared__ float Vt[32][100];
  __shared__ float Ps[16][34];
  __shared__ float Pl[16][34];
  const int bh = blockIdx.y, b = bh >> 2, h = bh & 3;
  const int pk = blockIdx.x;                 // pair id 0..31
  const int tid = threadIdx.x, j = tid & 15, rg = tid >> 4;
  const float a = 1.f / (1.f + expf(-fgp[0]));
#pragma unroll 1
  for (int side = 0; side < 2; ++side) {
    const int qt = side ? (63 - pk) : pk;    // tiles k and 63-k
    const int t0 = qt << 4;
    const int t = t0 + rg;
    const size_t qbase = ((size_t)bh * TT + t0) * DD;
    __syncthreads();
#pragma unroll
    for (int p = 0; p < 6; ++p) {
      const int i = tid + 256 * p, r = i / 96, d = i - r * 96;
      Qt[r][d] = qr[qbase + i];
      Qpt[r][d] = qp[qbase + i];
    }
    float accS[6] = {}, accN[6] = {};
    float mrow = -1e30f, lrow = 0.f, den = 0.f;
    const int nc = (qt >> 1) + 1;
    __syncthreads();
    for (int c = 0; c < nc; ++c) {
      const int s0 = c << 5;
      const float* vb = qkv + ((size_t)(b * TT + s0)) * QKVN + 2 * CC + h * DD;
      const size_t kb = ((size_t)bh * TT + s0) * DD;
#pragma unroll
      for (int p = 0; p < 12; ++p) {
        const int i = tid + 256 * p, s = i / 96, d = i - s * 96;
        Kt[s][d] = kr[kb + i];
        Kpt[s][d] = kp[kb + i];
        Vt[s][d] = vb[(size_t)s * QKVN + d];
      }
      __syncthreads();
      float ds0 = 0.f, ds1 = 0.f, dl0 = 0.f, dl1 = 0.f;
#pragma unroll
      for (int dd = 0; dd < 96; dd += 4) {
        const float4 qa = *(const float4*)&Qt[rg][dd];
        const float4 ka = *(const float4*)&Kt[j][dd];
        const float4 k2 = *(const float4*)&Kt[j + 16][dd];
        ds0 += dot4f(qa, ka); ds1 += dot4f(qa, k2);
        const float4 pa = *(const float4*)&Qpt[rg][dd];
        const float4 fa = *(const float4*)&Kpt[j][dd];
        const float4 f2 = *(const float4*)&Kpt[j + 16][dd];
        dl0 += dot4f(pa, fa); dl1 += dot4f(pa, f2);
      }
      const float scale = 0.10206207261596577f;
      float sc0 = ds0 * scale, sc1 = ds1 * scale;
      if (c == nc - 1) {                     // diagonal chunk: mask s > t
        if (s0 + j > t)      { sc0 = -1e30f; dl0 = 0.f; }
        if (s0 + j + 16 > t) { sc1 = -1e30f; dl1 = 0.f; }
      }
      const float cm = rmax16(fmaxf(sc0, sc1));
      const float mn = fmaxf(mrow, cm);
      const float sf = expf(mrow - mn);
      const float p0 = expf(sc0 - mn), p1 = expf(sc1 - mn);
      lrow = lrow * sf + rsum16(p0 + p1);
      mrow = mn;
      den += rsum16(dl0 + dl1);
#pragma unroll
      for (int u = 0; u < 6; ++u) accS[u] *= sf;
      Ps[rg][j] = p0; Ps[rg][j + 16] = p1;
      Pl[rg][j] = dl0; Pl[rg][j + 16] = dl1;
      __syncthreads();
      const int c0 = j * 6;
#pragma unroll
      for (int s = 0; s < 32; s += 2) {
        const float2 pA = *(const float2*)&Ps[rg][s];
        const float2 lA = *(const float2*)&Pl[rg][s];
        const float* v0p = &Vt[s][c0];
        const float* v1p = v0p + 100;
        float va[6], vb2[6];
        *(float2*)&va[0] = *(const float2*)(v0p);
        *(float2*)&va[2] = *(const float2*)(v0p + 2);
        *(float2*)&va[4] = *(const float2*)(v0p + 4);
        *(float2*)&vb2[0] = *(const float2*)(v1p);
        *(float2*)&vb2[2] = *(const float2*)(v1p + 2);
        *(float2*)&vb2[4] = *(const float2*)(v1p + 4);
#pragma unroll
        for (int u = 0; u < 6; ++u) {
          accS[u] += pA.x * va[u] + pA.y * vb2[u];
          accN[u] += lA.x * va[u] + lA.y * vb2[u];
        }
      }
      __syncthreads();
    }
    const float invl = 1.0f / lrow;
    const float dinv = 1.0f / (den + 1e-4f);
    float yl[6];
    float s1 = 0.f;
#pragma unroll
    for (int u = 0; u < 6; ++u) { yl[u] = accN[u] * dinv; s1 += yl[u]; }
    s1 = rsum16(s1);
    const float mu = s1 * (1.f / DD);
    float s2 = 0.f;
#pragma unroll
    for (int u = 0; u < 6; ++u) { const float d = yl[u] - mu; s2 += d * d; }
    s2 = rsum16(s2);
    const float rr = rsqrtf(s2 * (1.f / DD) + 1e-5f);
    const size_t ob = ((size_t)(b * TT + t)) * CC + h * DD + j * 6;
#pragma unroll
    for (int u = 0; u < 6; ++u) {
      const float ylin = (yl[u] - mu) * rr * ang[j * 6 + u] + anb[j * 6 + u];
      const float ys = accS[u] * invl;
      y_attn[ob + u] = a * ys + (1.f - a) * ylin;
    }
  }
}

// ---------- kernel: out-LN + HBS + residual + LN2 + gate top-2 ----------
// Gate logits from fp32 xbuf (routing-critical); xn2 bf16 only feeds the
// expert GEMMs (smooth, bf16-safe).
__global__ __launch_bounds__(128) void hbs_kernel(
    const float* __restrict__ y_attn, const float* __restrict__ x,
    const float* __restrict__ outg, const float* __restrict__ outb,
    const float* __restrict__ preg, const float* __restrict__ preb,
    const float* __restrict__ blocks, const float* __restrict__ wrow,
    const float* __restrict__ wcol, const float* __restrict__ alphap,
    const float* __restrict__ biasv, const float* __restrict__ ln2g,
    const float* __restrict__ ln2b, const float* __restrict__ gatew,
    float* __restrict__ hout, unsigned short* __restrict__ xn2,
    int* __restrict__ tok_idx, float* __restrict__ tok_w, int* __restrict__ counts) {
  __shared__ float flatS[CC];
  __shared__ float ybuf[CC];
  __shared__ float xbuf[CC];
  __shared__ float tmp[400];
  __shared__ float red[2];
  __shared__ float logit[EE];
  const int row = blockIdx.x, tid = threadIdx.x;
  const size_t base = (size_t)row * CC;
  float v[3];
#pragma unroll
  for (int p = 0; p < 3; ++p) v[p] = y_attn[base + tid + 128 * p];
  float s = blockRed128(v[0] + v[1] + v[2], red);
  float mu = s * (1.f / CC);
  float sq = 0.f;
#pragma unroll
  for (int p = 0; p < 3; ++p) { const float d = v[p] - mu; sq += d * d; }
  sq = blockRed128(sq, red);
  float rin = rsqrtf(sq * (1.f / CC) + 1e-5f);
  float w[3];
#pragma unroll
  for (int p = 0; p < 3; ++p) {
    const int c = tid + 128 * p;
    w[p] = (v[p] - mu) * rin * outg[c] + outb[c];
  }
  s = blockRed128(w[0] + w[1] + w[2], red);
  mu = s * (1.f / CC);
  sq = 0.f;
#pragma unroll
  for (int p = 0; p < 3; ++p) { const float d = w[p] - mu; sq += d * d; }
  sq = blockRed128(sq, red);
  rin = rsqrtf(sq * (1.f / CC) + 1e-5f);
#pragma unroll
  for (int p = 0; p < 3; ++p) {
    const int c = tid + 128 * p;
    flatS[c] = (w[p] - mu) * rin * preg[c] + preb[c];
  }
  __syncthreads();
#pragma unroll
  for (int p = 0; p < 3; ++p) {
    const int o = tid + 128 * p;
    const int g = o >> 4, cc = o & 15;
    const float* bp = blocks + g * 256 + cc;
    const float* fp = flatS + g * 16;
    float acc = 0.f;
#pragma unroll
    for (int bb = 0; bb < 16; ++bb) acc += fp[bb] * bp[bb * 16];
    ybuf[o] = acc;
  }
#pragma unroll
  for (int p = 0; p < 4; ++p) {
    const int o = tid + 128 * p;
    if (o < 400) {
      const int i = o / 20, k = o - i * 20;
      float acc = 0.f;
#pragma unroll
      for (int jj = 0; jj < 20; ++jj) {
        const int src = i * 20 + jj;
        const float gv = (src < CC) ? flatS[src] : 0.f;
        acc += gv * wcol[jj * 20 + k];
      }
      tmp[o] = acc;
    }
  }
  __syncthreads();
  const float alpha = alphap[0];
  float hr[3];
#pragma unroll
  for (int p = 0; p < 3; ++p) {
    const int o = tid + 128 * p;
    const int i = o / 20, ll = o - i * 20;
    float mon = 0.f;
#pragma unroll
    for (int k = 0; k < 20; ++k) mon += tmp[i * 20 + k] * wrow[ll * 20 + k];
    const float hb = ybuf[383 - o] + alpha * mon + biasv[o];
    const float hv = x[base + o] + hb;
    hout[base + o] = hv;
    hr[p] = hv;
  }
  s = blockRed128(hr[0] + hr[1] + hr[2], red);
  mu = s * (1.f / CC);
  sq = 0.f;
#pragma unroll
  for (int p = 0; p < 3; ++p) { const float d = hr[p] - mu; sq += d * d; }
  sq = blockRed128(sq, red);
  rin = rsqrtf(sq * (1.f / CC) + 1e-5f);
#pragma unroll
  for (int p = 0; p < 3; ++p) {
    const int c = tid + 128 * p;
    const float xv = (hr[p] - mu) * rin * ln2g[c] + ln2b[c];
    xn2[base + c] = f2bf(xv);
    xbuf[c] = xv;
  }
  __syncthreads();
  const int e = tid >> 4, jj = tid & 15;
  float part = 0.f;
  for (int c = jj; c < CC; c += 16) part += xbuf[c] * gatew[c * EE + e];
  part = rsum16(part);
  if (jj == 0) logit[e] = fminf(20.f, fmaxf(-20.f, part));
  __syncthreads();
  if (tid == 0) {
    float lg[EE];
#pragma unroll
    for (int ee = 0; ee < EE; ++ee) lg[ee] = logit[ee];
    int i0 = 0; float v0 = lg[0];
#pragma unroll
    for (int ee = 1; ee < EE; ++ee) if (lg[ee] > v0) { v0 = lg[ee]; i0 = ee; }
    int i1 = -1; float v1 = -1e30f;
#pragma unroll
    for (int ee = 0; ee < EE; ++ee)
      if (ee != i0 && lg[ee] > v1) { v1 = lg[ee]; i1 = ee; }
    const float e1 = expf(v1 - v0);
    const float w0 = 1.f / (1.f + e1), w1 = e1 / (1.f + e1);
    tok_idx[2 * row] = i0; tok_idx[2 * row + 1] = i1;
    tok_w[2 * row] = w0; tok_w[2 * row + 1] = w1;
    atomicAdd(&counts[i0], 1);
    atomicAdd(&counts[i1], 1);
  }
}

// ---------- routing ----------
__global__ void r_offsets_kernel(const int* __restrict__ counts, int* offsets, int* cursor) {
  if (threadIdx.x == 0) {
    int acc = 0;
    for (int e = 0; e < EE; ++e) { offsets[e] = acc; cursor[e] = acc; acc += counts[e]; }
  }
}
__global__ __launch_bounds__(256) void r_scatter_kernel(
    const int* __restrict__ tok_idx, const float* __restrict__ tok_w,
    int* cursor, int* __restrict__ perm, float* __restrict__ slotw,
    int* __restrict__ dest) {
  const int n = blockIdx.x * 256 + threadIdx.x;
  if (n >= NROW) return;
#pragma unroll
  for (int k = 0; k < 2; ++k) {
    const int e = tok_idx[2 * n + k];
    const int pos = atomicAdd(&cursor[e], 1);
    perm[pos] = n;
    slotw[pos] = tok_w[2 * n + k];
    dest[pos] = 2 * n + k;
  }
}

// ---------- MFMA GEMM notes (MoE only) ----------
// Tile 64x64, 4 waves (2x2 of 32x32), K-step 32, mfma_f32_16x16x32_bf16.
// A and Bt both [rows][K] bf16: A-frag row=lane&15, k=(lane>>4)*8+i;
// B-frag col=lane&15, same k; C/D col=lane&15, row=(lane>>4)*4+reg
// (HW-verified m89 family). LDS pitch 40 shorts: 2-way aliasing (free).

// ---------- MoE GEMM1 (bf16 MFMA): gathered xn2 @ w1T[e] + b1 -> gelu -> bf16 hbuf ----------
__global__ __launch_bounds__(256) void gemm_moe1_kernel(
    const unsigned short* __restrict__ xn2b, const unsigned short* __restrict__ w1t,
    const float* __restrict__ b1, const int* __restrict__ perm,
    const int* __restrict__ offsets, const int* __restrict__ counts,
    unsigned short* __restrict__ hbuf) {
  const int e = blockIdx.z;
  const int cnt = counts[e];
  const int m0 = blockIdx.y * 64;
  if (m0 >= cnt) return;
  const int n0 = blockIdx.x * 64;
  const int off = offsets[e];
  __shared__ __align__(16) short As[64][40];
  __shared__ __align__(16) short Bs[64][40];
  const int t = threadIdx.x;
  const int srow = t >> 2, sko = (t & 3) * 8;
  const int w = t >> 6, lane = t & 63, lm = lane & 15, kg8 = (lane >> 4) * 8;
  const int wr = (w >> 1) * 32, wc = (w & 1) * 32;
  const int sm = m0 + srow;
  const int grow = perm[off + (sm < cnt ? sm : cnt - 1)];
  const unsigned short* aro = xn2b + (size_t)grow * CC;
  const unsigned short* bro = w1t + ((size_t)e * FFD + n0 + srow) * CC;
  f32x4 acc[2][2] = {};
  for (int k0 = 0; k0 < CC; k0 += 32) {
    *(float4*)&As[srow][sko] = *(const float4*)(aro + k0 + sko);
    *(float4*)&Bs[srow][sko] = *(const float4*)(bro + k0 + sko);
    __syncthreads();
    const bf16x8 a0 = *(const bf16x8*)&As[wr + lm][kg8];
    const bf16x8 a1 = *(const bf16x8*)&As[wr + lm + 16][kg8];
    const bf16x8 b0 = *(const bf16x8*)&Bs[wc + lm][kg8];
    const bf16x8 b1v = *(const bf16x8*)&Bs[wc + lm + 16][kg8];
    acc[0][0] = __builtin_amdgcn_mfma_f32_16x16x32_bf16(a0, b0, acc[0][0], 0, 0, 0);
    acc[0][1] = __builtin_amdgcn_mfma_f32_16x16x32_bf16(a0, b1v, acc[0][1], 0, 0, 0);
    acc[1][0] = __builtin_amdgcn_mfma_f32_16x16x32_bf16(a1, b0, acc[1][0], 0, 0, 0);
    acc[1][1] = __builtin_amdgcn_mfma_f32_16x16x32_bf16(a1, b1v, acc[1][1], 0, 0, 0);
    __syncthreads();
  }
#pragma unroll
  for (int mi = 0; mi < 2; ++mi)
#pragma unroll
    for (int r = 0; r < 4; ++r) {
      const int m = m0 + wr + mi * 16 + (lane >> 4) * 4 + r;
      if (m < cnt) {
#pragma unroll
        for (int ni = 0; ni < 2; ++ni) {
          const int c = n0 + wc + ni * 16 + lm;
          const float tv = acc[mi][ni][r] + b1[e * FFD + c];
          const float gel = 0.5f * tv * (1.0f + erff(tv * 0.70710678118654752f));
          hbuf[(size_t)(off + m) * FFD + c] = f2bf(gel);
        }
      }
    }
}

// ---------- MoE GEMM2 (bf16 MFMA): hbuf @ w2T[e] + b2 -> *w -> slot_out fp32 ----------
__global__ __launch_bounds__(256) void gemm_moe2_kernel(
    const unsigned short* __restrict__ hbuf, const unsigned short* __restrict__ w2t,
    const float* __restrict__ b2, const int* __restrict__ offsets,
    const int* __restrict__ counts, const int* __restrict__ dest,
    const float* __restrict__ slotw, float* __restrict__ so) {
  const int e = blockIdx.z;
  const int cnt = counts[e];
  const int m0 = blockIdx.y * 64;
  if (m0 >= cnt) return;
  const int n0 = blockIdx.x * 64;
  const int off = offsets[e];
  __shared__ __align__(16) short As[64][40];
  __shared__ __align__(16) short Bs[64][40];
  const int t = threadIdx.x;
  const int srow = t >> 2, sko = (t & 3) * 8;
  const int w = t >> 6, lane = t & 63, lm = lane & 15, kg8 = (lane >> 4) * 8;
  const int wr = (w >> 1) * 32, wc = (w & 1) * 32;
  const int sm = m0 + srow;
  const unsigned short* aro = hbuf + (size_t)(off + (sm < cnt ? sm : cnt - 1)) * FFD;
  const unsigned short* bro = w2t + ((size_t)e * CC + n0 + srow) * FFD;
  f32x4 acc[2][2] = {};
  for (int k0 = 0; k0 < FFD; k0 += 32) {
    *(float4*)&As[srow][sko] = *(const float4*)(aro + k0 + sko);
    *(float4*)&Bs[srow][sko] = *(const float4*)(bro + k0 + sko);
    __syncthreads();
    const bf16x8 a0 = *(const bf16x8*)&As[wr + lm][kg8];
    const bf16x8 a1 = *(const bf16x8*)&As[wr + lm + 16][kg8];
    const bf16x8 b0 = *(const bf16x8*)&Bs[wc + lm][kg8];
    const bf16x8 b1v = *(const bf16x8*)&Bs[wc + lm + 16][kg8];
    acc[0][0] = __builtin_amdgcn_mfma_f32_16x16x32_bf16(a0, b0, acc[0][0], 0, 0, 0);
    acc[0][1] = __builtin_amdgcn_mfma_f32_16x16x32_bf16(a0, b1v, acc[0][1], 0, 0, 0);
    acc[1][0] = __builtin_amdgcn_mfma_f32_16x16x32_bf16(a1, b0, acc[1][0], 0, 0, 0);
    acc[1][1] = __builtin_amdgcn_mfma_f32_16x16x32_bf16(a1, b1v, acc[1][1], 0, 0, 0);
    __syncthreads();
  }
#pragma unroll
  for (int mi = 0; mi < 2; ++mi)
#pragma unroll
    for (int r = 0; r < 4; ++r) {
      const int m = m0 + wr + mi * 16 + (lane >> 4) * 4 + r;
      if (m < cnt) {
        const int sIdx = off + m;
        const int dd = dest[sIdx];
        const float wv = slotw[sIdx];
#pragma unroll
        for (int ni = 0; ni < 2; ++ni) {
          const int c = n0 + wc + ni * 16 + lm;
          so[(size_t)dd * CC + c] = wv * (acc[mi][ni][r] + b2[e * CC + c]);
        }
      }
    }
}

// ---------- final: out = h + slot0 + slot1 ----------
__global__ __launch_bounds__(256) void final_kernel(
    const float* __restrict__ h, const float* __restrict__ so,
    float* __restrict__ out) {
  const int i = blockIdx.x * 256 + threadIdx.x;  // float4 index, NROW*96
  const int n = i / 96, c = i - n * 96;
  const float4* h4 = (const float4*)h;
  const float4* s4 = (const float4*)so;
  float4* o4 = (float4*)out;
  const float4 a = h4[i];
  const float4 b0 = s4[(size_t)n * 192 + c];
  const float4 b1 = s4[(size_t)n * 192 + 96 + c];
  o4[i] = make_float4(a.x + b0.x + b1.x, a.y + b0.y + b1.y,
                      a.z + b0.z + b1.z, a.w + b0.w + b1.w);
}

// ---------- host ----------
// Workspace (lifetime-aliased, ~60 MB; >=66 MB proven available round 2):
//   region A [0,3MiB): xn fp32 (ln->qkv)  ALIAS yat fp32 (attn->hbs)
//   region B: qkv|qr|kr|qp|kp fp32 (->attn)  ALIAS hmid bf16 (moe1->moe2)
//   then hbufr, xn2(bf16), so, routing, w1T/w2T bf16 weights.
extern "C" void kernel_launch(void* const* d_in, const int* in_sizes, int n_in,
                              void* d_out, int out_size, void* d_ws, size_t ws_size,
                              hipStream_t stream) {
  const float* x          = (const float*)d_in[0];
  const float* ln1_g      = (const float*)d_in[1];
  const float* ln1_b      = (const float*)d_in[2];
  const float* ln2_g      = (const float*)d_in[3];
  const float* ln2_b      = (const float*)d_in[4];
  const float* qkv_w      = (const float*)d_in[5];
  const float* qkv_b      = (const float*)d_in[6];
  const float* pre_g      = (const float*)d_in[7];
  const float* pre_b      = (const float*)d_in[8];
  const float* blocks     = (const float*)d_in[9];
  const float* wrow       = (const float*)d_in[10];
  const float* wcol       = (const float*)d_in[11];
  const float* alpha      = (const float*)d_in[12];
  const float* biasv      = (const float*)d_in[13];
  const float* ang        = (const float*)d_in[14];
  const float* anb        = (const float*)d_in[15];
  const float* outg       = (const float*)d_in[16];
  const float* outb       = (const float*)d_in[17];
  const float* fg         = (const float*)d_in[18];
  const float* gatew      = (const float*)d_in[19];
  const float* w1         = (const float*)d_in[20];
  const float* b1         = (const float*)d_in[21];
  const float* w2         = (const float*)d_in[22];
  const float* b2         = (const float*)d_in[23];
  float* out = (float*)d_out;

  char* ws = (char*)d_ws;
  constexpr size_t SZ_ROWC  = (size_t)NROW * CC * 4;          // 3 MiB
  constexpr size_t SZ_QKV   = (size_t)NROW * QKVN * 4;        // 9 MiB
  constexpr size_t SZ_HEAD  = (size_t)BB * HH * TT * DD * 4;  // 3 MiB
  constexpr size_t SZ_HMID  = (size_t)NSLOT * FFD * 4;        // 24 MiB region reach
  constexpr size_t OFF_A    = 0;                               // xn / yat
  constexpr size_t OFF_B    = OFF_A + SZ_ROWC;                 // qkv.. / hmid
  constexpr size_t OFF_QR   = OFF_B + SZ_QKV;
  constexpr size_t OFF_KR   = OFF_QR + SZ_HEAD;
  constexpr size_t OFF_QP   = OFF_KR + SZ_HEAD;
  constexpr size_t OFF_KP   = OFF_QP + SZ_HEAD;
  constexpr size_t OFF_HB   = OFF_B + SZ_HMID;                 // hbufr
  constexpr size_t OFF_XN2  = OFF_HB + SZ_ROWC;
  constexpr size_t OFF_SO   = OFF_XN2 + SZ_ROWC;
  constexpr size_t OFF_TI   = OFF_SO + (size_t)NSLOT * CC * 4;
  constexpr size_t OFF_TW   = OFF_TI + NSLOT * 4;
  constexpr size_t OFF_PERM = OFF_TW + NSLOT * 4;
  constexpr size_t OFF_SW   = OFF_PERM + NSLOT * 4;
  constexpr size_t OFF_DEST = OFF_SW + NSLOT * 4;
  constexpr size_t OFF_CNT  = OFF_DEST + NSLOT * 4;
  constexpr size_t OFF_OFFS = OFF_CNT + 256;
  constexpr size_t OFF_CUR  = OFF_OFFS + 256;
  constexpr size_t OFF_W1T  = OFF_CUR + 256;
  constexpr size_t OFF_W2T  = OFF_W1T + (size_t)EE * FFD * CC * 2;

  float* xn    = (float*)(ws + OFF_A);
  float* yat   = (float*)(ws + OFF_A);     // alias: xn dead after gemm_qkv
  float* qkv   = (float*)(ws + OFF_B);
  float* qr    = (float*)(ws + OFF_QR);
  float* kr    = (float*)(ws + OFF_KR);
  float* qp    = (float*)(ws + OFF_QP);
  float* kp    = (float*)(ws + OFF_KP);
  unsigned short* hmid = (unsigned short*)(ws + OFF_B);  // alias after attn
  float* hbufr = (float*)(ws + OFF_HB);
  unsigned short* xn2b = (unsigned short*)(ws + OFF_XN2);
  float* so    = (float*)(ws + OFF_SO);
  int*   tok_idx = (int*)(ws + OFF_TI);
  float* tok_w   = (float*)(ws + OFF_TW);
  int*   perm    = (int*)(ws + OFF_PERM);
  float* slotw   = (float*)(ws + OFF_SW);
  int*   dest    = (int*)(ws + OFF_DEST);
  int*   counts  = (int*)(ws + OFF_CNT);
  int*   offsets = (int*)(ws + OFF_OFFS);
  int*   cursor  = (int*)(ws + OFF_CUR);
  unsigned short* w1T  = (unsigned short*)(ws + OFF_W1T);
  unsigned short* w2T  = (unsigned short*)(ws + OFF_W2T);

  zero_counts_kernel<<<1, 64, 0, stream>>>(counts);
  transconv_kernel<<<dim3(FFD / 32, CC / 32, EE), 256, 0, stream>>>(w1, w1T, CC, FFD);
  transconv_kernel<<<dim3(CC / 32, FFD / 32, EE), 256, 0, stream>>>(w2, w2T, FFD, CC);
  ln_row_kernel<<<NROW, 64, 0, stream>>>(x, ln1_g, ln1_b, xn);
  gemm_qkv_kernel<<<dim3(QKVN / 64, NROW / 64), 256, 0, stream>>>(xn, qkv_w, qkv_b, qkv);
  rope_kernel<<<(BB * HH * TT * 48) / 256, 256, 0, stream>>>(qkv, qr, kr, qp, kp);
  attn_kernel<<<dim3(32, BB * HH), 256, 0, stream>>>(qr, kr, qp, kp, qkv, ang, anb, fg, yat);
  hbs_kernel<<<NROW, 128, 0, stream>>>(yat, x, outg, outb, pre_g, pre_b, blocks,
                                       wrow, wcol, alpha, biasv, ln2_g, ln2_b,
                                       gatew, hbufr, xn2b, tok_idx, tok_w, counts);
  r_offsets_kernel<<<1, 64, 0, stream>>>(counts, offsets, cursor);
  r_scatter_kernel<<<NROW / 256, 256, 0, stream>>>(tok_idx, tok_w, cursor, perm, slotw, dest);
  gemm_moe1_kernel<<<dim3(FFD / 64, NROW / 64, EE), 256, 0, stream>>>(
      xn2b, w1T, b1, perm, offsets, counts, hmid);
  gemm_moe2_kernel<<<dim3(CC / 64, NROW / 64, EE), 256, 0, stream>>>(
      hmid, w2T, b2, offsets, counts, dest, slotw, so);
  final_kernel<<<(NROW * CC / 4) / 256, 256, 0, stream>>>(hbufr, so, out);
}